// Round 1
// baseline (701.101 us; speedup 1.0000x reference)
//
#include <hip/hip_runtime.h>
#include <cstdint>
#include <cstddef>

#define NN 20000
#define INDIM 256
#define HIDC 128
#define NCLS 64

__device__ __forceinline__ float lrelu(float x) { return x >= 0.f ? x : 0.2f * x; }

// ---------------- CSR build (counting sort by dst) ----------------

__global__ void hist_kernel(const int* __restrict__ ei, int E, int N, int* __restrict__ cnt) {
  int i = blockIdx.x * 256 + threadIdx.x;
  if (i < E + N) {
    int dst = (i < E) ? ei[E + i] : (i - E);
    atomicAdd(&cnt[dst], 1);
  }
}

__global__ __launch_bounds__(1024) void scan_kernel(const int* __restrict__ cnt,
                                                    int* __restrict__ row_ptr,
                                                    int* __restrict__ cursor, int n) {
  __shared__ int wsum[16];
  const int t = threadIdx.x;
  const int lane = t & 63, w = t >> 6;
  int carry = 0;
  for (int base = 0; base < n; base += 1024) {
    int i = base + t;
    int v = (i < n) ? cnt[i] : 0;
    int x = v;
#pragma unroll
    for (int d = 1; d < 64; d <<= 1) {
      int y = __shfl_up(x, d);
      if (lane >= d) x += y;
    }
    if (lane == 63) wsum[w] = x;
    __syncthreads();
    if (t < 16) {
      int s = wsum[t];
#pragma unroll
      for (int d = 1; d < 16; d <<= 1) {
        int y = __shfl_up(s, d);
        if (t >= d) s += y;
      }
      wsum[t] = s;
    }
    __syncthreads();
    int blocksum = wsum[15];
    int wprefix = (w == 0) ? 0 : wsum[w - 1];
    int excl = carry + wprefix + (x - v);
    if (i < n) { row_ptr[i] = excl; cursor[i] = excl; }
    carry += blocksum;
    __syncthreads();
  }
  if (t == 0) row_ptr[n] = carry;
}

__global__ void scatter_kernel(const int* __restrict__ ei, int E, int N,
                               int* __restrict__ cursor, int* __restrict__ col) {
  int i = blockIdx.x * 256 + threadIdx.x;
  if (i < E + N) {
    int src, dst;
    if (i < E) { src = ei[i]; dst = ei[E + i]; }
    else       { src = i - E; dst = src; }
    int slot = atomicAdd(&cursor[dst], 1);
    col[slot] = src;
  }
}

// ---------------- generic fp32 GEMM: C = act(A@B + bias) ----------------
// A [M,K] row-major, B [K,N] row-major. N % 64 == 0, K % 16 == 0. M guarded.
// act: 0=none, 1=relu, 2=sigmoid. bias may be null.

__global__ __launch_bounds__(256) void gemm_f32(const float* __restrict__ A,
                                                const float* __restrict__ B,
                                                const float* __restrict__ bias,
                                                float* __restrict__ C,
                                                int M, int N, int K, int act) {
  __shared__ float As[64][17];  // [m][k], pad to kill bank conflicts
  __shared__ float Bs[16][65];  // [k][n]
  const int t = threadIdx.x;
  const int tx = t & 15;   // n dim (x4)
  const int ty = t >> 4;   // m dim (x4)
  const int bm = blockIdx.x * 64;
  const int bn = blockIdx.y * 64;

  const int am = t >> 2;          // 0..63
  const int kq = (t & 3) * 4;     // 0,4,8,12
  const int bk = t >> 4;          // 0..15
  const int nq = (t & 15) * 4;    // 0..60

  const int arow = bm + am;
  float acc[4][4] = {};

  for (int k0 = 0; k0 < K; k0 += 16) {
    float4 av = make_float4(0.f, 0.f, 0.f, 0.f);
    if (arow < M) av = *(const float4*)&A[(size_t)arow * K + k0 + kq];
    As[am][kq + 0] = av.x; As[am][kq + 1] = av.y;
    As[am][kq + 2] = av.z; As[am][kq + 3] = av.w;
    float4 bv = *(const float4*)&B[(size_t)(k0 + bk) * N + bn + nq];
    Bs[bk][nq + 0] = bv.x; Bs[bk][nq + 1] = bv.y;
    Bs[bk][nq + 2] = bv.z; Bs[bk][nq + 3] = bv.w;
    __syncthreads();
#pragma unroll
    for (int k = 0; k < 16; ++k) {
      float a0 = As[ty * 4 + 0][k], a1 = As[ty * 4 + 1][k];
      float a2 = As[ty * 4 + 2][k], a3 = As[ty * 4 + 3][k];
      float b0 = Bs[k][tx * 4 + 0], b1 = Bs[k][tx * 4 + 1];
      float b2 = Bs[k][tx * 4 + 2], b3 = Bs[k][tx * 4 + 3];
      acc[0][0] += a0 * b0; acc[0][1] += a0 * b1; acc[0][2] += a0 * b2; acc[0][3] += a0 * b3;
      acc[1][0] += a1 * b0; acc[1][1] += a1 * b1; acc[1][2] += a1 * b2; acc[1][3] += a1 * b3;
      acc[2][0] += a2 * b0; acc[2][1] += a2 * b1; acc[2][2] += a2 * b2; acc[2][3] += a2 * b3;
      acc[3][0] += a3 * b0; acc[3][1] += a3 * b1; acc[3][2] += a3 * b2; acc[3][3] += a3 * b3;
    }
    __syncthreads();
  }

#pragma unroll
  for (int i = 0; i < 4; ++i) {
    int r = bm + ty * 4 + i;
    if (r < M) {
#pragma unroll
      for (int j = 0; j < 4; ++j) {
        int cidx = bn + tx * 4 + j;
        float v = acc[i][j];
        if (bias) v += bias[cidx];
        if (act == 1) v = fmaxf(v, 0.f);
        else if (act == 2) v = 1.f / (1.f + __expf(-v));
        C[(size_t)r * N + cidx] = v;
      }
    }
  }
}

// ---------------- per-node attention logits: as/ad = <h[n,h,:], a_src/dst[h,:]> --------

template <int H>
__global__ __launch_bounds__(128) void calc_alpha(const float* __restrict__ h,
                                                  const float* __restrict__ a_src,
                                                  const float* __restrict__ a_dst,
                                                  float* __restrict__ as_out,
                                                  float* __restrict__ ad_out) {
  const int n = blockIdx.x;
  const int t = threadIdx.x;
  const int lane = t & 63, w = t >> 6;
  __shared__ float sps[2], spd[2];
#pragma unroll
  for (int head = 0; head < H; ++head) {
    float v = h[(size_t)n * (H * HIDC) + head * HIDC + t];
    float ps = v * a_src[head * HIDC + t];
    float pd = v * a_dst[head * HIDC + t];
#pragma unroll
    for (int d = 32; d > 0; d >>= 1) {
      ps += __shfl_down(ps, d);
      pd += __shfl_down(pd, d);
    }
    if (lane == 0) { sps[w] = ps; spd[w] = pd; }
    __syncthreads();
    if (t == 0) {
      as_out[n * H + head] = sps[0] + sps[1];
      ad_out[n * H + head] = spd[0] + spd[1];
    }
    __syncthreads();
  }
}

// ---------------- GAT aggregation, H=4, fused head-mean + bias + BN + ReLU ----------------

__global__ __launch_bounds__(256) void gat_agg4(const float* __restrict__ h,
                                                const float* __restrict__ as,
                                                const float* __restrict__ ad,
                                                const int* __restrict__ rp,
                                                const int* __restrict__ cs,
                                                const float* __restrict__ bias,
                                                const float* __restrict__ bng,
                                                const float* __restrict__ bnb,
                                                const float* __restrict__ bnm,
                                                const float* __restrict__ bnv,
                                                float* __restrict__ out) {
  const int n = blockIdx.x;
  const int t = threadIdx.x;
  const int lane = t & 63, w = t >> 6;
  __shared__ float redm[4][4];
  __shared__ float m_s[4], den_s[4];
  __shared__ float wls[64][4];
  __shared__ int srcs[64];
  __shared__ float red[256];

  const int r0 = rp[n], r1 = rp[n + 1];
  float adv[4];
#pragma unroll
  for (int hh = 0; hh < 4; ++hh) adv[hh] = ad[n * 4 + hh];

  // pass 1: per-head max
  float mloc[4] = {-1e30f, -1e30f, -1e30f, -1e30f};
  for (int i = r0 + t; i < r1; i += 256) {
    int s = cs[i];
#pragma unroll
    for (int hh = 0; hh < 4; ++hh)
      mloc[hh] = fmaxf(mloc[hh], lrelu(as[s * 4 + hh] + adv[hh]));
  }
#pragma unroll
  for (int hh = 0; hh < 4; ++hh) {
    float v = mloc[hh];
#pragma unroll
    for (int d = 32; d > 0; d >>= 1) v = fmaxf(v, __shfl_down(v, d));
    if (lane == 0) redm[w][hh] = v;
  }
  __syncthreads();
  if (t < 4) m_s[t] = fmaxf(fmaxf(redm[0][t], redm[1][t]), fmaxf(redm[2][t], redm[3][t]));
  __syncthreads();
  float mh[4];
#pragma unroll
  for (int hh = 0; hh < 4; ++hh) mh[hh] = m_s[hh];

  // pass 2: per-head denom
  float dloc[4] = {0.f, 0.f, 0.f, 0.f};
  for (int i = r0 + t; i < r1; i += 256) {
    int s = cs[i];
#pragma unroll
    for (int hh = 0; hh < 4; ++hh)
      dloc[hh] += __expf(lrelu(as[s * 4 + hh] + adv[hh]) - mh[hh]);
  }
#pragma unroll
  for (int hh = 0; hh < 4; ++hh) {
    float v = dloc[hh];
#pragma unroll
    for (int d = 32; d > 0; d >>= 1) v += __shfl_down(v, d);
    if (lane == 0) redm[w][hh] = v;
  }
  __syncthreads();
  if (t < 4) den_s[t] = redm[0][t] + redm[1][t] + redm[2][t] + redm[3][t];
  __syncthreads();
  float dinv[4];
#pragma unroll
  for (int hh = 0; hh < 4; ++hh) dinv[hh] = 1.f / (den_s[hh] + 1e-16f);

  // pass 3: weighted aggregation, chunks of 64 edges staged in LDS
  const int h0 = t >> 7;  // 0 or 1 (this thread covers heads h0 and h0+2)
  float acc0 = 0.f, acc1 = 0.f;
  for (int base = r0; base < r1; base += 64) {
    int nedge = min(64, r1 - base);
    if (t < nedge) {
      int s = cs[base + t];
      srcs[t] = s;
#pragma unroll
      for (int hh = 0; hh < 4; ++hh) {
        float e = lrelu(as[s * 4 + hh] + adv[hh]);
        wls[t][hh] = __expf(e - mh[hh]) * dinv[hh];
      }
    }
    __syncthreads();
    for (int j = 0; j < nedge; ++j) {
      int s = srcs[j];
      const float* hp = h + (size_t)s * 512;
      acc0 += wls[j][h0] * hp[t];
      acc1 += wls[j][h0 + 2] * hp[t + 256];
    }
    __syncthreads();
  }

  // head mean + bias + BN + relu
  red[t] = acc0 + acc1;
  __syncthreads();
  if (t < 128) {
    float v = (red[t] + red[t + 128]) * 0.25f + bias[t];
    float x = bng[t] * (v - bnm[t]) * rsqrtf(bnv[t] + 1e-5f) + bnb[t];
    out[(size_t)n * 128 + t] = fmaxf(x, 0.f);
  }
}

// ---------------- GAT aggregation, H=1, concat (just + bias) ----------------

__global__ __launch_bounds__(128) void gat_agg1(const float* __restrict__ h,
                                                const float* __restrict__ as,
                                                const float* __restrict__ ad,
                                                const int* __restrict__ rp,
                                                const int* __restrict__ cs,
                                                const float* __restrict__ bias,
                                                float* __restrict__ out) {
  const int n = blockIdx.x;
  const int t = threadIdx.x;
  const int lane = t & 63, w = t >> 6;
  __shared__ float red2[2];
  __shared__ float wls[64];
  __shared__ int srcs[64];

  const int r0 = rp[n], r1 = rp[n + 1];
  const float adv = ad[n];

  float mloc = -1e30f;
  for (int i = r0 + t; i < r1; i += 128)
    mloc = fmaxf(mloc, lrelu(as[cs[i]] + adv));
#pragma unroll
  for (int d = 32; d > 0; d >>= 1) mloc = fmaxf(mloc, __shfl_down(mloc, d));
  if (lane == 0) red2[w] = mloc;
  __syncthreads();
  const float m = fmaxf(red2[0], red2[1]);
  __syncthreads();

  float dloc = 0.f;
  for (int i = r0 + t; i < r1; i += 128)
    dloc += __expf(lrelu(as[cs[i]] + adv) - m);
#pragma unroll
  for (int d = 32; d > 0; d >>= 1) dloc += __shfl_down(dloc, d);
  if (lane == 0) red2[w] = dloc;
  __syncthreads();
  const float dinv = 1.f / (red2[0] + red2[1] + 1e-16f);

  float acc = 0.f;
  for (int base = r0; base < r1; base += 64) {
    int nedge = min(64, r1 - base);
    if (t < nedge) {
      int s = cs[base + t];
      srcs[t] = s;
      wls[t] = __expf(lrelu(as[s] + adv) - m) * dinv;
    }
    __syncthreads();
    for (int j = 0; j < nedge; ++j)
      acc += wls[j] * h[(size_t)srcs[j] * 128 + t];
    __syncthreads();
  }
  out[(size_t)n * 128 + t] = acc + bias[t];
}

// ---------------- launch ----------------

extern "C" void kernel_launch(void* const* d_in, const int* in_sizes, int n_in,
                              void* d_out, int out_size, void* d_ws, size_t ws_size,
                              hipStream_t stream) {
  const float* x      = (const float*)d_in[0];
  const int*   ei     = (const int*)d_in[1];
  const float* W1     = (const float*)d_in[2];
  const float* a_src1 = (const float*)d_in[3];
  const float* a_dst1 = (const float*)d_in[4];
  const float* b1     = (const float*)d_in[5];
  const float* W2     = (const float*)d_in[6];
  const float* a_src2 = (const float*)d_in[7];
  const float* a_dst2 = (const float*)d_in[8];
  const float* b2     = (const float*)d_in[9];
  const float* W3     = (const float*)d_in[10];
  const float* a_src3 = (const float*)d_in[11];
  const float* a_dst3 = (const float*)d_in[12];
  const float* b3     = (const float*)d_in[13];
  const float* bn1g = (const float*)d_in[14];
  const float* bn1b = (const float*)d_in[15];
  const float* bn1m = (const float*)d_in[16];
  const float* bn1v = (const float*)d_in[17];
  const float* bn2g = (const float*)d_in[18];
  const float* bn2b = (const float*)d_in[19];
  const float* bn2m = (const float*)d_in[20];
  const float* bn2v = (const float*)d_in[21];
  const float* l1w = (const float*)d_in[22];
  const float* l1b = (const float*)d_in[23];
  const float* l2w = (const float*)d_in[24];
  const float* l2b = (const float*)d_in[25];
  const float* l3w = (const float*)d_in[26];
  const float* l3b = (const float*)d_in[27];
  float* out = (float*)d_out;

  const int N = NN;
  const int E = in_sizes[1] / 2;  // 320000
  const int ET = E + N;

  // workspace carve (256B aligned)
  char* p = (char*)d_ws;
  auto carve = [&](size_t bytes) {
    char* q = p;
    p += (bytes + 255) & ~(size_t)255;
    return q;
  };
  float* h_big = (float*)carve((size_t)N * 512 * 4);  // also reused as [N,64] MLP buf
  float* f1    = (float*)carve((size_t)N * 128 * 4);
  float* f2    = (float*)carve((size_t)N * 128 * 4);
  float* asb   = (float*)carve((size_t)N * 4 * 4);
  float* adb   = (float*)carve((size_t)N * 4 * 4);
  int* cnt     = (int*)carve((size_t)N * 4);
  int* cursor  = (int*)carve((size_t)N * 4);
  int* row_ptr = (int*)carve((size_t)(N + 1) * 4);
  int* col     = (int*)carve((size_t)ET * 4);
  (void)ws_size; (void)n_in; (void)out_size;

  // --- CSR build (same graph reused for all 3 GAT layers) ---
  hipMemsetAsync(cnt, 0, (size_t)N * 4, stream);
  int eb = (ET + 255) / 256;
  hist_kernel<<<eb, 256, 0, stream>>>(ei, E, N, cnt);
  scan_kernel<<<1, 1024, 0, stream>>>(cnt, row_ptr, cursor, N);
  scatter_kernel<<<eb, 256, 0, stream>>>(ei, E, N, cursor, col);

  // --- GAT layer 1 ---
  gemm_f32<<<dim3((N + 63) / 64, 512 / 64), 256, 0, stream>>>(x, W1, nullptr, h_big, N, 512, INDIM, 0);
  calc_alpha<4><<<N, 128, 0, stream>>>(h_big, a_src1, a_dst1, asb, adb);
  gat_agg4<<<N, 256, 0, stream>>>(h_big, asb, adb, row_ptr, col, b1, bn1g, bn1b, bn1m, bn1v, f1);

  // --- GAT layer 2 ---
  gemm_f32<<<dim3((N + 63) / 64, 512 / 64), 256, 0, stream>>>(f1, W2, nullptr, h_big, N, 512, HIDC, 0);
  calc_alpha<4><<<N, 128, 0, stream>>>(h_big, a_src2, a_dst2, asb, adb);
  gat_agg4<<<N, 256, 0, stream>>>(h_big, asb, adb, row_ptr, col, b2, bn2g, bn2b, bn2m, bn2v, f2);

  // --- GAT layer 3 (H=1, concat) ---
  gemm_f32<<<dim3((N + 63) / 64, 128 / 64), 256, 0, stream>>>(f2, W3, nullptr, h_big, N, 128, HIDC, 0);
  calc_alpha<1><<<N, 128, 0, stream>>>(h_big, a_src3, a_dst3, asb, adb);
  gat_agg1<<<N, 128, 0, stream>>>(h_big, asb, adb, row_ptr, col, b3, f1);

  // --- classifier MLP ---
  gemm_f32<<<dim3((N + 63) / 64, 128 / 64), 256, 0, stream>>>(f1, l1w, l1b, f2, N, 128, 128, 1);
  gemm_f32<<<dim3((N + 63) / 64, 64 / 64), 256, 0, stream>>>(f2, l2w, l2b, h_big, N, 64, 128, 1);
  gemm_f32<<<dim3((N + 63) / 64, 64 / 64), 256, 0, stream>>>(h_big, l3w, l3b, out, N, 64, 64, 2);
}

// Round 2
// 494.495 us; speedup vs baseline: 1.4178x; 1.4178x over previous
//
#include <hip/hip_runtime.h>
#include <cstdint>
#include <cstddef>

#define NN 20000

typedef __bf16 bf16_t;
typedef __bf16 bf16x8 __attribute__((ext_vector_type(8)));
typedef __bf16 bf16x4 __attribute__((ext_vector_type(4)));
typedef float f32x4 __attribute__((ext_vector_type(4)));

#define AS1 __attribute__((address_space(1)))
#define AS3 __attribute__((address_space(3)))

__device__ __forceinline__ float lrelu(float x) { return x >= 0.f ? x : 0.2f * x; }
__device__ __forceinline__ float bflo(uint32_t u) { return __uint_as_float(u << 16); }
__device__ __forceinline__ float bfhi(uint32_t u) { return __uint_as_float(u & 0xffff0000u); }

// ---------------- CSR build (counting sort by dst) ----------------

__global__ void hist_kernel(const int* __restrict__ ei, int E, int N, int* __restrict__ cnt) {
  int i = blockIdx.x * 256 + threadIdx.x;
  if (i < E + N) {
    int dst = (i < E) ? ei[E + i] : (i - E);
    atomicAdd(&cnt[dst], 1);
  }
}

__global__ __launch_bounds__(1024) void scan_kernel(const int* __restrict__ cnt,
                                                    int* __restrict__ row_ptr,
                                                    int* __restrict__ cursor, int n) {
  __shared__ int wsum[16];
  const int t = threadIdx.x;
  const int lane = t & 63, w = t >> 6;
  int carry = 0;
  for (int base = 0; base < n; base += 1024) {
    int i = base + t;
    int v = (i < n) ? cnt[i] : 0;
    int x = v;
#pragma unroll
    for (int d = 1; d < 64; d <<= 1) {
      int y = __shfl_up(x, d);
      if (lane >= d) x += y;
    }
    if (lane == 63) wsum[w] = x;
    __syncthreads();
    if (t < 16) {
      int s = wsum[t];
#pragma unroll
      for (int d = 1; d < 16; d <<= 1) {
        int y = __shfl_up(s, d);
        if (t >= d) s += y;
      }
      wsum[t] = s;
    }
    __syncthreads();
    int blocksum = wsum[15];
    int wprefix = (w == 0) ? 0 : wsum[w - 1];
    int excl = carry + wprefix + (x - v);
    if (i < n) { row_ptr[i] = excl; cursor[i] = excl; }
    carry += blocksum;
    __syncthreads();
  }
  if (t == 0) row_ptr[n] = carry;
}

__global__ void scatter_kernel(const int* __restrict__ ei, int E, int N,
                               int* __restrict__ cursor, int* __restrict__ col) {
  int i = blockIdx.x * 256 + threadIdx.x;
  if (i < E + N) {
    int src, dst;
    if (i < E) { src = ei[i]; dst = ei[E + i]; }
    else       { src = i - E; dst = src; }
    int slot = atomicAdd(&cursor[dst], 1);
    col[slot] = src;
  }
}

// ---------------- dtype conversion ----------------

__global__ void cast_bf16_kernel(const float* __restrict__ in, bf16_t* __restrict__ out, int n4) {
  int i = blockIdx.x * 256 + threadIdx.x;
  if (i < n4) {
    float4 v = ((const float4*)in)[i];
    bf16x4 o;
    o.x = (bf16_t)v.x; o.y = (bf16_t)v.y; o.z = (bf16_t)v.z; o.w = (bf16_t)v.w;
    ((bf16x4*)out)[i] = o;
  }
}

// W [K,N] fp32 -> Wt [N,K] bf16 (K,N multiples of 32)
__global__ void transpose_cast(const float* __restrict__ W, bf16_t* __restrict__ Wt,
                               int K, int N) {
  __shared__ float tile[32][33];
  const int bx = blockIdx.x * 32;  // n
  const int by = blockIdx.y * 32;  // k
  const int tx = threadIdx.x, ty = threadIdx.y;
#pragma unroll
  for (int i = 0; i < 32; i += 8)
    tile[ty + i][tx] = W[(size_t)(by + ty + i) * N + bx + tx];
  __syncthreads();
#pragma unroll
  for (int i = 0; i < 32; i += 8)
    Wt[(size_t)(bx + ty + i) * K + by + tx] = (bf16_t)tile[tx][ty + i];
}

// ---------------- bf16 MFMA GEMM: C = act(A @ Bt^T + bias) ----------------
// A [M,K] bf16 row-major (M guarded), Bt [N,K] bf16 row-major. K%64==0, N%TN==0.
// ACT: 0=none, 1=relu, 2=sigmoid. OUT_T: float or bf16_t.

template <int TN, int ACT, typename OUT_T>
__global__ __launch_bounds__(256) void gemm_mfma(const bf16_t* __restrict__ A,
                                                 const bf16_t* __restrict__ Bt,
                                                 const float* __restrict__ bias,
                                                 OUT_T* __restrict__ C,
                                                 int M, int N, int K) {
  constexpr int TM = 128, BK = 64;
  constexpr int MT = (TN == 128) ? 4 : 2;
  constexpr int NRB = (TN * BK * 2) / 4096;  // global_load_lds rounds per wave for B
  __shared__ __align__(16) bf16_t As[TM * BK];
  __shared__ __align__(16) bf16_t Bs[TN * BK];

  const int t = threadIdx.x;
  const int wave = t >> 6, lane = t & 63;
  const int ln15 = lane & 15, quad = lane >> 4;
  const int bm = blockIdx.x * TM;
  const int bn = blockIdx.y * TN;
  const int wm = (TN == 128) ? (wave >> 1) * 64 : wave * 32;
  const int wn = (TN == 128) ? (wave & 1) * 64 : 0;
  const int rowLimA = M - 1 - bm;  // >= 0 since bm < M
  const size_t strideAB = (size_t)K * 2;

  f32x4 acc[MT][4];
#pragma unroll
  for (int mi = 0; mi < MT; ++mi)
#pragma unroll
    for (int ni = 0; ni < 4; ++ni) acc[mi][ni] = (f32x4){0.f, 0.f, 0.f, 0.f};

  const char* gA = (const char*)(A + (size_t)bm * K);
  const char* gB = (const char*)(Bt + (size_t)bn * K);

  for (int k0 = 0; k0 < K; k0 += BK) {
    // stage A tile 128x64 bf16 (16 KB): 4 waves x 4 rounds x 1024 B
#pragma unroll
    for (int r = 0; r < 4; ++r) {
      int base = (wave * 4 + r) * 1024;   // wave-uniform LDS byte offset
      int flat = base + lane * 16;
      int row = flat >> 7;                // 128 B per row
      int grow = row < rowLimA ? row : rowLimA;
      const char* gp = gA + (size_t)grow * strideAB + (size_t)(k0 * 2) + (flat & 127);
      __builtin_amdgcn_global_load_lds((const AS1 void*)gp,
                                       (AS3 void*)((char*)As + base), 16, 0, 0);
    }
    // stage B tile TNx64 bf16
#pragma unroll
    for (int r = 0; r < NRB; ++r) {
      int base = (wave * NRB + r) * 1024;
      int flat = base + lane * 16;
      int row = flat >> 7;
      const char* gp = gB + (size_t)row * strideAB + (size_t)(k0 * 2) + (flat & 127);
      __builtin_amdgcn_global_load_lds((const AS1 void*)gp,
                                       (AS3 void*)((char*)Bs + base), 16, 0, 0);
    }
    __syncthreads();
#pragma unroll
    for (int kk = 0; kk < BK; kk += 32) {
      bf16x8 af[MT], bfr[4];
#pragma unroll
      for (int mi = 0; mi < MT; ++mi)
        af[mi] = *(const bf16x8*)&As[(wm + mi * 16 + ln15) * BK + kk + quad * 8];
#pragma unroll
      for (int ni = 0; ni < 4; ++ni)
        bfr[ni] = *(const bf16x8*)&Bs[(wn + ni * 16 + ln15) * BK + kk + quad * 8];
#pragma unroll
      for (int mi = 0; mi < MT; ++mi)
#pragma unroll
        for (int ni = 0; ni < 4; ++ni)
          acc[mi][ni] = __builtin_amdgcn_mfma_f32_16x16x32_bf16(af[mi], bfr[ni], acc[mi][ni], 0, 0, 0);
    }
    __syncthreads();
  }

  // epilogue: C/D layout col=lane&15, row=quad*4+reg
#pragma unroll
  for (int mi = 0; mi < MT; ++mi) {
    int r0 = bm + wm + mi * 16 + quad * 4;
#pragma unroll
    for (int ni = 0; ni < 4; ++ni) {
      int c = bn + wn + ni * 16 + ln15;
      float bv = bias ? bias[c] : 0.f;
#pragma unroll
      for (int reg = 0; reg < 4; ++reg) {
        int r = r0 + reg;
        if (r < M) {
          float v = acc[mi][ni][reg] + bv;
          if (ACT == 1) v = fmaxf(v, 0.f);
          else if (ACT == 2) v = 1.f / (1.f + __expf(-v));
          C[(size_t)r * N + c] = (OUT_T)v;
        }
      }
    }
  }
}

// ---------------- attention logits ----------------
// H=4: one wave per head, lane covers a bf16 pair. No LDS.
__global__ __launch_bounds__(256) void calc_alpha4(const bf16_t* __restrict__ h,
                                                   const float* __restrict__ a_src,
                                                   const float* __restrict__ a_dst,
                                                   float* __restrict__ as_out,
                                                   float* __restrict__ ad_out) {
  const int n = blockIdx.x, t = threadIdx.x;
  const int head = t >> 6, lane = t & 63;
  const int c0 = lane * 2;
  uint32_t pv = *(const uint32_t*)&h[(size_t)n * 512 + head * 128 + c0];
  float v0 = bflo(pv), v1 = bfhi(pv);
  float ps = v0 * a_src[head * 128 + c0] + v1 * a_src[head * 128 + c0 + 1];
  float pd = v0 * a_dst[head * 128 + c0] + v1 * a_dst[head * 128 + c0 + 1];
#pragma unroll
  for (int d = 32; d > 0; d >>= 1) { ps += __shfl_down(ps, d); pd += __shfl_down(pd, d); }
  if (lane == 0) { as_out[n * 4 + head] = ps; ad_out[n * 4 + head] = pd; }
}

__global__ __launch_bounds__(64) void calc_alpha1(const bf16_t* __restrict__ h,
                                                  const float* __restrict__ a_src,
                                                  const float* __restrict__ a_dst,
                                                  float* __restrict__ as_out,
                                                  float* __restrict__ ad_out) {
  const int n = blockIdx.x, t = threadIdx.x;
  const int c0 = t * 2;
  uint32_t pv = *(const uint32_t*)&h[(size_t)n * 128 + c0];
  float v0 = bflo(pv), v1 = bfhi(pv);
  float ps = v0 * a_src[c0] + v1 * a_src[c0 + 1];
  float pd = v0 * a_dst[c0] + v1 * a_dst[c0 + 1];
#pragma unroll
  for (int d = 32; d > 0; d >>= 1) { ps += __shfl_down(ps, d); pd += __shfl_down(pd, d); }
  if (t == 0) { as_out[n] = ps; ad_out[n] = pd; }
}

// ---------------- GAT aggregation, H=4, fused head-mean + bias + BN + ReLU ----------------

__global__ __launch_bounds__(256) void gat_agg4(const bf16_t* __restrict__ h,
                                                const float* __restrict__ as,
                                                const float* __restrict__ ad,
                                                const int* __restrict__ rp,
                                                const int* __restrict__ cs,
                                                const float* __restrict__ bias,
                                                const float* __restrict__ bng,
                                                const float* __restrict__ bnb,
                                                const float* __restrict__ bnm,
                                                const float* __restrict__ bnv,
                                                bf16_t* __restrict__ out) {
  const int n = blockIdx.x;
  const int t = threadIdx.x;
  const int lane = t & 63, w = t >> 6;
  __shared__ float redm[4][4];
  __shared__ float m_s[4], den_s[4];
  __shared__ float wls[64][4];
  __shared__ int srcs[64];
  __shared__ float sm[4][128];

  const int r0 = rp[n], r1 = rp[n + 1];
  float adv[4];
#pragma unroll
  for (int hh = 0; hh < 4; ++hh) adv[hh] = ad[n * 4 + hh];

  // pass 1: per-head max
  float mloc[4] = {-1e30f, -1e30f, -1e30f, -1e30f};
  for (int i = r0 + t; i < r1; i += 256) {
    int s = cs[i];
#pragma unroll
    for (int hh = 0; hh < 4; ++hh)
      mloc[hh] = fmaxf(mloc[hh], lrelu(as[s * 4 + hh] + adv[hh]));
  }
#pragma unroll
  for (int hh = 0; hh < 4; ++hh) {
    float v = mloc[hh];
#pragma unroll
    for (int d = 32; d > 0; d >>= 1) v = fmaxf(v, __shfl_down(v, d));
    if (lane == 0) redm[w][hh] = v;
  }
  __syncthreads();
  if (t < 4) m_s[t] = fmaxf(fmaxf(redm[0][t], redm[1][t]), fmaxf(redm[2][t], redm[3][t]));
  __syncthreads();
  float mh[4];
#pragma unroll
  for (int hh = 0; hh < 4; ++hh) mh[hh] = m_s[hh];

  // pass 2: per-head denom
  float dloc[4] = {0.f, 0.f, 0.f, 0.f};
  for (int i = r0 + t; i < r1; i += 256) {
    int s = cs[i];
#pragma unroll
    for (int hh = 0; hh < 4; ++hh)
      dloc[hh] += __expf(lrelu(as[s * 4 + hh] + adv[hh]) - mh[hh]);
  }
#pragma unroll
  for (int hh = 0; hh < 4; ++hh) {
    float v = dloc[hh];
#pragma unroll
    for (int d = 32; d > 0; d >>= 1) v += __shfl_down(v, d);
    if (lane == 0) redm[w][hh] = v;
  }
  __syncthreads();
  if (t < 4) den_s[t] = redm[0][t] + redm[1][t] + redm[2][t] + redm[3][t];
  __syncthreads();
  float dinv[4];
#pragma unroll
  for (int hh = 0; hh < 4; ++hh) dinv[hh] = 1.f / (den_s[hh] + 1e-16f);

  // pass 3: weighted gather; wave w handles head w, lane covers a bf16 pair
  const int head = w;
  const int c0 = lane * 2;
  float acc0 = 0.f, acc1 = 0.f;
  for (int base = r0; base < r1; base += 64) {
    int nedge = min(64, r1 - base);
    if (t < nedge) {
      int s = cs[base + t];
      srcs[t] = s;
#pragma unroll
      for (int hh = 0; hh < 4; ++hh) {
        float e = lrelu(as[s * 4 + hh] + adv[hh]);
        wls[t][hh] = __expf(e - mh[hh]) * dinv[hh];
      }
    }
    __syncthreads();
    for (int j = 0; j < nedge; ++j) {
      uint32_t pv = *(const uint32_t*)&h[(size_t)srcs[j] * 512 + head * 128 + c0];
      float wj = wls[j][head];
      acc0 += wj * bflo(pv);
      acc1 += wj * bfhi(pv);
    }
    __syncthreads();
  }

  sm[head][c0] = acc0;
  sm[head][c0 + 1] = acc1;
  __syncthreads();
  if (t < 128) {
    float v = (sm[0][t] + sm[1][t] + sm[2][t] + sm[3][t]) * 0.25f + bias[t];
    float x = bng[t] * (v - bnm[t]) * rsqrtf(bnv[t] + 1e-5f) + bnb[t];
    out[(size_t)n * 128 + t] = (bf16_t)fmaxf(x, 0.f);
  }
}

// ---------------- GAT aggregation, H=1 (single wave) ----------------

__global__ __launch_bounds__(64) void gat_agg1(const bf16_t* __restrict__ h,
                                               const float* __restrict__ as,
                                               const float* __restrict__ ad,
                                               const int* __restrict__ rp,
                                               const int* __restrict__ cs,
                                               const float* __restrict__ bias,
                                               bf16_t* __restrict__ out) {
  const int n = blockIdx.x, t = threadIdx.x;
  __shared__ float wls[64];
  __shared__ int srcs[64];
  const int r0 = rp[n], r1 = rp[n + 1];
  const float adv = ad[n];

  float mloc = -1e30f;
  for (int i = r0 + t; i < r1; i += 64) mloc = fmaxf(mloc, lrelu(as[cs[i]] + adv));
#pragma unroll
  for (int d = 32; d > 0; d >>= 1) mloc = fmaxf(mloc, __shfl_down(mloc, d));
  const float m = __shfl(mloc, 0);

  float dloc = 0.f;
  for (int i = r0 + t; i < r1; i += 64) dloc += __expf(lrelu(as[cs[i]] + adv) - m);
#pragma unroll
  for (int d = 32; d > 0; d >>= 1) dloc += __shfl_down(dloc, d);
  const float dinv = 1.f / (__shfl(dloc, 0) + 1e-16f);

  const int c0 = t * 2;
  float acc0 = 0.f, acc1 = 0.f;
  for (int base = r0; base < r1; base += 64) {
    int nedge = min(64, r1 - base);
    if (t < nedge) {
      int s = cs[base + t];
      srcs[t] = s;
      wls[t] = __expf(lrelu(as[s] + adv) - m) * dinv;
    }
    __syncthreads();
    for (int j = 0; j < nedge; ++j) {
      uint32_t pv = *(const uint32_t*)&h[(size_t)srcs[j] * 128 + c0];
      float wj = wls[j];
      acc0 += wj * bflo(pv);
      acc1 += wj * bfhi(pv);
    }
    __syncthreads();
  }
  out[(size_t)n * 128 + c0]     = (bf16_t)(acc0 + bias[c0]);
  out[(size_t)n * 128 + c0 + 1] = (bf16_t)(acc1 + bias[c0 + 1]);
}

// ---------------- launch ----------------

extern "C" void kernel_launch(void* const* d_in, const int* in_sizes, int n_in,
                              void* d_out, int out_size, void* d_ws, size_t ws_size,
                              hipStream_t stream) {
  const float* x      = (const float*)d_in[0];
  const int*   ei     = (const int*)d_in[1];
  const float* W1     = (const float*)d_in[2];
  const float* a_src1 = (const float*)d_in[3];
  const float* a_dst1 = (const float*)d_in[4];
  const float* b1     = (const float*)d_in[5];
  const float* W2     = (const float*)d_in[6];
  const float* a_src2 = (const float*)d_in[7];
  const float* a_dst2 = (const float*)d_in[8];
  const float* b2     = (const float*)d_in[9];
  const float* W3     = (const float*)d_in[10];
  const float* a_src3 = (const float*)d_in[11];
  const float* a_dst3 = (const float*)d_in[12];
  const float* b3     = (const float*)d_in[13];
  const float* bn1g = (const float*)d_in[14];
  const float* bn1b = (const float*)d_in[15];
  const float* bn1m = (const float*)d_in[16];
  const float* bn1v = (const float*)d_in[17];
  const float* bn2g = (const float*)d_in[18];
  const float* bn2b = (const float*)d_in[19];
  const float* bn2m = (const float*)d_in[20];
  const float* bn2v = (const float*)d_in[21];
  const float* l1w = (const float*)d_in[22];
  const float* l1b = (const float*)d_in[23];
  const float* l2w = (const float*)d_in[24];
  const float* l2b = (const float*)d_in[25];
  const float* l3w = (const float*)d_in[26];
  const float* l3b = (const float*)d_in[27];
  float* out = (float*)d_out;

  const int N = NN;
  const int E = in_sizes[1] / 2;
  const int ET = E + N;

  char* p = (char*)d_ws;
  auto carve = [&](size_t bytes) {
    char* q = p;
    p += (bytes + 255) & ~(size_t)255;
    return q;
  };
  bf16_t* xb   = (bf16_t*)carve((size_t)N * 256 * 2);
  bf16_t* hbig = (bf16_t*)carve((size_t)N * 512 * 2);
  bf16_t* f1b  = (bf16_t*)carve((size_t)N * 128 * 2);
  bf16_t* f2b  = (bf16_t*)carve((size_t)N * 128 * 2);
  bf16_t* g3b  = (bf16_t*)carve((size_t)N * 128 * 2);
  bf16_t* m1b  = (bf16_t*)carve((size_t)N * 128 * 2);
  bf16_t* m2b  = (bf16_t*)carve((size_t)N * 64 * 2);
  float* asb   = (float*)carve((size_t)N * 4 * 4);
  float* adb   = (float*)carve((size_t)N * 4 * 4);
  int* cnt     = (int*)carve((size_t)N * 4);
  int* cursor  = (int*)carve((size_t)N * 4);
  int* row_ptr = (int*)carve((size_t)(N + 1) * 4);
  int* col     = (int*)carve((size_t)ET * 4);
  bf16_t* W1t = (bf16_t*)carve((size_t)512 * 256 * 2);
  bf16_t* W2t = (bf16_t*)carve((size_t)512 * 128 * 2);
  bf16_t* W3t = (bf16_t*)carve((size_t)128 * 128 * 2);
  bf16_t* l1t = (bf16_t*)carve((size_t)128 * 128 * 2);
  bf16_t* l2t = (bf16_t*)carve((size_t)64 * 128 * 2);
  bf16_t* l3t = (bf16_t*)carve((size_t)64 * 64 * 2);
  (void)ws_size; (void)n_in; (void)out_size;

  // --- CSR build ---
  hipMemsetAsync(cnt, 0, (size_t)N * 4, stream);
  int eb = (ET + 255) / 256;
  hist_kernel<<<eb, 256, 0, stream>>>(ei, E, N, cnt);
  scan_kernel<<<1, 1024, 0, stream>>>(cnt, row_ptr, cursor, N);
  scatter_kernel<<<eb, 256, 0, stream>>>(ei, E, N, cursor, col);

  // --- dtype prep ---
  cast_bf16_kernel<<<(N * 256 / 4 + 255) / 256, 256, 0, stream>>>(x, xb, N * 256 / 4);
  transpose_cast<<<dim3(16, 8), dim3(32, 8), 0, stream>>>(W1, W1t, 256, 512);
  transpose_cast<<<dim3(16, 4), dim3(32, 8), 0, stream>>>(W2, W2t, 128, 512);
  transpose_cast<<<dim3(4, 4),  dim3(32, 8), 0, stream>>>(W3, W3t, 128, 128);
  transpose_cast<<<dim3(4, 4),  dim3(32, 8), 0, stream>>>(l1w, l1t, 128, 128);
  transpose_cast<<<dim3(2, 4),  dim3(32, 8), 0, stream>>>(l2w, l2t, 128, 64);
  transpose_cast<<<dim3(2, 2),  dim3(32, 8), 0, stream>>>(l3w, l3t, 64, 64);

  const int gm = (N + 127) / 128;  // 157

  // --- GAT layer 1 ---
  gemm_mfma<128, 0, bf16_t><<<dim3(gm, 4), 256, 0, stream>>>(xb, W1t, nullptr, hbig, N, 512, 256);
  calc_alpha4<<<N, 256, 0, stream>>>(hbig, a_src1, a_dst1, asb, adb);
  gat_agg4<<<N, 256, 0, stream>>>(hbig, asb, adb, row_ptr, col, b1, bn1g, bn1b, bn1m, bn1v, f1b);

  // --- GAT layer 2 ---
  gemm_mfma<128, 0, bf16_t><<<dim3(gm, 4), 256, 0, stream>>>(f1b, W2t, nullptr, hbig, N, 512, 128);
  calc_alpha4<<<N, 256, 0, stream>>>(hbig, a_src2, a_dst2, asb, adb);
  gat_agg4<<<N, 256, 0, stream>>>(hbig, asb, adb, row_ptr, col, b2, bn2g, bn2b, bn2m, bn2v, f2b);

  // --- GAT layer 3 (H=1) ---
  gemm_mfma<128, 0, bf16_t><<<dim3(gm, 1), 256, 0, stream>>>(f2b, W3t, nullptr, hbig, N, 128, 128);
  calc_alpha1<<<N, 64, 0, stream>>>(hbig, a_src3, a_dst3, asb, adb);
  gat_agg1<<<N, 64, 0, stream>>>(hbig, asb, adb, row_ptr, col, b3, g3b);

  // --- classifier MLP ---
  gemm_mfma<128, 1, bf16_t><<<dim3(gm, 1), 256, 0, stream>>>(g3b, l1t, l1b, m1b, N, 128, 128);
  gemm_mfma<64, 1, bf16_t><<<dim3(gm, 1), 256, 0, stream>>>(m1b, l2t, l2b, m2b, N, 64, 128);
  gemm_mfma<64, 2, float><<<dim3(gm, 1), 256, 0, stream>>>(m2b, l3t, l3b, out, N, 64, 64);
}

// Round 3
// 426.949 us; speedup vs baseline: 1.6421x; 1.1582x over previous
//
#include <hip/hip_runtime.h>
#include <cstdint>
#include <cstddef>

#define NN 20000

typedef __bf16 bf16_t;
typedef __bf16 bf16x8 __attribute__((ext_vector_type(8)));
typedef __bf16 bf16x4 __attribute__((ext_vector_type(4)));
typedef float f32x4 __attribute__((ext_vector_type(4)));

#define AS1 __attribute__((address_space(1)))
#define AS3 __attribute__((address_space(3)))

__device__ __forceinline__ float lrelu(float x) { return x >= 0.f ? x : 0.2f * x; }
__device__ __forceinline__ float bflo(uint32_t u) { return __uint_as_float(u << 16); }
__device__ __forceinline__ float bfhi(uint32_t u) { return __uint_as_float(u & 0xffff0000u); }

__device__ __forceinline__ uint32_t pack2bf(float a, float b) {
  bf16_t x = (bf16_t)a, y = (bf16_t)b;
  uint16_t ux = __builtin_bit_cast(uint16_t, x);
  uint16_t uy = __builtin_bit_cast(uint16_t, y);
  return (uint32_t)ux | ((uint32_t)uy << 16);
}

// ---------------- CSR build (counting sort by dst) ----------------

__global__ void hist_kernel(const int* __restrict__ ei, int E, int N, int* __restrict__ cnt) {
  int i = blockIdx.x * 256 + threadIdx.x;
  if (i < E + N) {
    int dst = (i < E) ? ei[E + i] : (i - E);
    atomicAdd(&cnt[dst], 1);
  }
}

__global__ __launch_bounds__(1024) void scan_kernel(const int* __restrict__ cnt,
                                                    int* __restrict__ row_ptr,
                                                    int* __restrict__ cursor, int n) {
  __shared__ int wsum[16];
  const int t = threadIdx.x;
  const int lane = t & 63, w = t >> 6;
  int carry = 0;
  for (int base = 0; base < n; base += 1024) {
    int i = base + t;
    int v = (i < n) ? cnt[i] : 0;
    int x = v;
#pragma unroll
    for (int d = 1; d < 64; d <<= 1) {
      int y = __shfl_up(x, d);
      if (lane >= d) x += y;
    }
    if (lane == 63) wsum[w] = x;
    __syncthreads();
    if (t < 16) {
      int s = wsum[t];
#pragma unroll
      for (int d = 1; d < 16; d <<= 1) {
        int y = __shfl_up(s, d);
        if (t >= d) s += y;
      }
      wsum[t] = s;
    }
    __syncthreads();
    int blocksum = wsum[15];
    int wprefix = (w == 0) ? 0 : wsum[w - 1];
    int excl = carry + wprefix + (x - v);
    if (i < n) { row_ptr[i] = excl; cursor[i] = excl; }
    carry += blocksum;
    __syncthreads();
  }
  if (t == 0) row_ptr[n] = carry;
}

__global__ void scatter_kernel(const int* __restrict__ ei, int E, int N,
                               int* __restrict__ cursor, int* __restrict__ col) {
  int i = blockIdx.x * 256 + threadIdx.x;
  if (i < E + N) {
    int src, dst;
    if (i < E) { src = ei[i]; dst = ei[E + i]; }
    else       { src = i - E; dst = src; }
    int slot = atomicAdd(&cursor[dst], 1);
    col[slot] = src;
  }
}

// ---------------- dtype conversion ----------------

__global__ void cast_bf16_kernel(const float* __restrict__ in, bf16_t* __restrict__ out, int n4) {
  int i = blockIdx.x * 256 + threadIdx.x;
  if (i < n4) {
    float4 v = ((const float4*)in)[i];
    bf16x4 o;
    o.x = (bf16_t)v.x; o.y = (bf16_t)v.y; o.z = (bf16_t)v.z; o.w = (bf16_t)v.w;
    ((bf16x4*)out)[i] = o;
  }
}

// W [K,N] fp32 -> Wt [N,K] bf16 (K,N multiples of 32)
__global__ void transpose_cast(const float* __restrict__ W, bf16_t* __restrict__ Wt,
                               int K, int N) {
  __shared__ float tile[32][33];
  const int bx = blockIdx.x * 32;  // n
  const int by = blockIdx.y * 32;  // k
  const int tx = threadIdx.x, ty = threadIdx.y;
#pragma unroll
  for (int i = 0; i < 32; i += 8)
    tile[ty + i][tx] = W[(size_t)(by + ty + i) * N + bx + tx];
  __syncthreads();
#pragma unroll
  for (int i = 0; i < 32; i += 8)
    Wt[(size_t)(bx + ty + i) * K + by + tx] = (bf16_t)tile[tx][ty + i];
}

// ---------------- bf16 MFMA GEMM: C = act(A @ Bt^T + bias) ----------------

template <int TN, int ACT, typename OUT_T>
__global__ __launch_bounds__(256) void gemm_mfma(const bf16_t* __restrict__ A,
                                                 const bf16_t* __restrict__ Bt,
                                                 const float* __restrict__ bias,
                                                 OUT_T* __restrict__ C,
                                                 int M, int N, int K) {
  constexpr int TM = 128, BK = 64;
  constexpr int MT = (TN == 128) ? 4 : 2;
  constexpr int NRB = (TN * BK * 2) / 4096;
  __shared__ __align__(16) bf16_t As[TM * BK];
  __shared__ __align__(16) bf16_t Bs[TN * BK];

  const int t = threadIdx.x;
  const int wave = t >> 6, lane = t & 63;
  const int ln15 = lane & 15, quad = lane >> 4;
  const int bm = blockIdx.x * TM;
  const int bn = blockIdx.y * TN;
  const int wm = (TN == 128) ? (wave >> 1) * 64 : wave * 32;
  const int wn = (TN == 128) ? (wave & 1) * 64 : 0;
  const int rowLimA = M - 1 - bm;
  const size_t strideAB = (size_t)K * 2;

  f32x4 acc[MT][4];
#pragma unroll
  for (int mi = 0; mi < MT; ++mi)
#pragma unroll
    for (int ni = 0; ni < 4; ++ni) acc[mi][ni] = (f32x4){0.f, 0.f, 0.f, 0.f};

  const char* gA = (const char*)(A + (size_t)bm * K);
  const char* gB = (const char*)(Bt + (size_t)bn * K);

  for (int k0 = 0; k0 < K; k0 += BK) {
#pragma unroll
    for (int r = 0; r < 4; ++r) {
      int base = (wave * 4 + r) * 1024;
      int flat = base + lane * 16;
      int row = flat >> 7;
      int grow = row < rowLimA ? row : rowLimA;
      const char* gp = gA + (size_t)grow * strideAB + (size_t)(k0 * 2) + (flat & 127);
      __builtin_amdgcn_global_load_lds((const AS1 void*)gp,
                                       (AS3 void*)((char*)As + base), 16, 0, 0);
    }
#pragma unroll
    for (int r = 0; r < NRB; ++r) {
      int base = (wave * NRB + r) * 1024;
      int flat = base + lane * 16;
      int row = flat >> 7;
      const char* gp = gB + (size_t)row * strideAB + (size_t)(k0 * 2) + (flat & 127);
      __builtin_amdgcn_global_load_lds((const AS1 void*)gp,
                                       (AS3 void*)((char*)Bs + base), 16, 0, 0);
    }
    __syncthreads();
#pragma unroll
    for (int kk = 0; kk < BK; kk += 32) {
      bf16x8 af[MT], bfr[4];
#pragma unroll
      for (int mi = 0; mi < MT; ++mi)
        af[mi] = *(const bf16x8*)&As[(wm + mi * 16 + ln15) * BK + kk + quad * 8];
#pragma unroll
      for (int ni = 0; ni < 4; ++ni)
        bfr[ni] = *(const bf16x8*)&Bs[(wn + ni * 16 + ln15) * BK + kk + quad * 8];
#pragma unroll
      for (int mi = 0; mi < MT; ++mi)
#pragma unroll
        for (int ni = 0; ni < 4; ++ni)
          acc[mi][ni] = __builtin_amdgcn_mfma_f32_16x16x32_bf16(af[mi], bfr[ni], acc[mi][ni], 0, 0, 0);
    }
    __syncthreads();
  }

#pragma unroll
  for (int mi = 0; mi < MT; ++mi) {
    int r0 = bm + wm + mi * 16 + quad * 4;
#pragma unroll
    for (int ni = 0; ni < 4; ++ni) {
      int c = bn + wn + ni * 16 + ln15;
      float bv = bias ? bias[c] : 0.f;
#pragma unroll
      for (int reg = 0; reg < 4; ++reg) {
        int r = r0 + reg;
        if (r < M) {
          float v = acc[mi][ni][reg] + bv;
          if (ACT == 1) v = fmaxf(v, 0.f);
          else if (ACT == 2) v = 1.f / (1.f + __expf(-v));
          C[(size_t)r * N + c] = (OUT_T)v;
        }
      }
    }
  }
}

// ---------------- attention logits (wave per node, 4 nodes/block) ----------------

__global__ __launch_bounds__(256) void calc_alpha4(const bf16_t* __restrict__ h,
                                                   const float* __restrict__ a_src,
                                                   const float* __restrict__ a_dst,
                                                   float* __restrict__ as_out,
                                                   float* __restrict__ ad_out) {
  const int wv = threadIdx.x >> 6, lane = threadIdx.x & 63;
  const int n = blockIdx.x * 4 + wv;
  const int c0 = lane * 8;
  const int head = lane >> 4;
  uint4 pv = *(const uint4*)&h[(size_t)n * 512 + c0];
  float4 s0 = *(const float4*)&a_src[c0];
  float4 s1 = *(const float4*)&a_src[c0 + 4];
  float4 d0 = *(const float4*)&a_dst[c0];
  float4 d1 = *(const float4*)&a_dst[c0 + 4];
  float v0 = bflo(pv.x), v1 = bfhi(pv.x), v2 = bflo(pv.y), v3 = bfhi(pv.y);
  float v4 = bflo(pv.z), v5 = bfhi(pv.z), v6 = bflo(pv.w), v7 = bfhi(pv.w);
  float ps = v0 * s0.x + v1 * s0.y + v2 * s0.z + v3 * s0.w
           + v4 * s1.x + v5 * s1.y + v6 * s1.z + v7 * s1.w;
  float pd = v0 * d0.x + v1 * d0.y + v2 * d0.z + v3 * d0.w
           + v4 * d1.x + v5 * d1.y + v6 * d1.z + v7 * d1.w;
#pragma unroll
  for (int d = 1; d < 16; d <<= 1) {
    ps += __shfl_xor(ps, d);
    pd += __shfl_xor(pd, d);
  }
  if ((lane & 15) == 0) {
    as_out[n * 4 + head] = ps;
    ad_out[n * 4 + head] = pd;
  }
}

__global__ __launch_bounds__(256) void calc_alpha1(const bf16_t* __restrict__ h,
                                                   const float* __restrict__ a_src,
                                                   const float* __restrict__ a_dst,
                                                   float* __restrict__ as_out,
                                                   float* __restrict__ ad_out) {
  const int wv = threadIdx.x >> 6, lane = threadIdx.x & 63;
  const int n = blockIdx.x * 4 + wv;
  const int c0 = lane * 2;
  uint32_t pv = *(const uint32_t*)&h[(size_t)n * 128 + c0];
  float v0 = bflo(pv), v1 = bfhi(pv);
  float ps = v0 * a_src[c0] + v1 * a_src[c0 + 1];
  float pd = v0 * a_dst[c0] + v1 * a_dst[c0 + 1];
#pragma unroll
  for (int d = 1; d < 64; d <<= 1) {
    ps += __shfl_xor(ps, d);
    pd += __shfl_xor(pd, d);
  }
  if (lane == 0) { as_out[n] = ps; ad_out[n] = pd; }
}

// ---------------- GAT aggregation, H=4: wave per node, dwordx4 pipelined gather -------

__global__ __launch_bounds__(256) void gat_agg4(const bf16_t* __restrict__ h,
                                                const float* __restrict__ as,
                                                const float* __restrict__ ad,
                                                const int* __restrict__ rp,
                                                const int* __restrict__ cs,
                                                const float* __restrict__ bias,
                                                const float* __restrict__ bng,
                                                const float* __restrict__ bnb,
                                                const float* __restrict__ bnm,
                                                const float* __restrict__ bnv,
                                                bf16_t* __restrict__ out) {
  const int wv = threadIdx.x >> 6, lane = threadIdx.x & 63;
  const int n = blockIdx.x * 4 + wv;
  const int myh = lane >> 4;  // head owning this lane's 8 cols
  __shared__ int sl[4][64];
  __shared__ float4 wl[4][64];

  const int r0 = rp[n], r1 = rp[n + 1];
  const float4 adv = *(const float4*)&ad[n * 4];

  // stats: per-head max then denom (wave-local, lanes stride over edges)
  float m0 = -1e30f, m1 = -1e30f, m2 = -1e30f, m3 = -1e30f;
  for (int i = r0 + lane; i < r1; i += 64) {
    const float4 av = *(const float4*)&as[cs[i] * 4];
    m0 = fmaxf(m0, lrelu(av.x + adv.x));
    m1 = fmaxf(m1, lrelu(av.y + adv.y));
    m2 = fmaxf(m2, lrelu(av.z + adv.z));
    m3 = fmaxf(m3, lrelu(av.w + adv.w));
  }
#pragma unroll
  for (int d = 1; d < 64; d <<= 1) {
    m0 = fmaxf(m0, __shfl_xor(m0, d));
    m1 = fmaxf(m1, __shfl_xor(m1, d));
    m2 = fmaxf(m2, __shfl_xor(m2, d));
    m3 = fmaxf(m3, __shfl_xor(m3, d));
  }
  float d0 = 0.f, d1 = 0.f, d2 = 0.f, d3 = 0.f;
  for (int i = r0 + lane; i < r1; i += 64) {
    const float4 av = *(const float4*)&as[cs[i] * 4];
    d0 += __expf(lrelu(av.x + adv.x) - m0);
    d1 += __expf(lrelu(av.y + adv.y) - m1);
    d2 += __expf(lrelu(av.z + adv.z) - m2);
    d3 += __expf(lrelu(av.w + adv.w) - m3);
  }
#pragma unroll
  for (int d = 1; d < 64; d <<= 1) {
    d0 += __shfl_xor(d0, d);
    d1 += __shfl_xor(d1, d);
    d2 += __shfl_xor(d2, d);
    d3 += __shfl_xor(d3, d);
  }
  const float i0 = 1.f / (d0 + 1e-16f), i1 = 1.f / (d1 + 1e-16f);
  const float i2 = 1.f / (d2 + 1e-16f), i3 = 1.f / (d3 + 1e-16f);

  // gather: wave handles full 1 KB row per edge (lane = 16 B), 4-deep pipeline
  const char* hb = (const char*)h;
  const size_t loff = (size_t)lane * 16;
  float acc[8] = {};

  for (int base = r0; base < r1; base += 64) {
    const int ne = min(64, r1 - base);
    if (lane < ne) {
      const int s = cs[base + lane];
      sl[wv][lane] = s;
      const float4 av = *(const float4*)&as[s * 4];
      wl[wv][lane] = make_float4(__expf(lrelu(av.x + adv.x) - m0) * i0,
                                 __expf(lrelu(av.y + adv.y) - m1) * i1,
                                 __expf(lrelu(av.z + adv.z) - m2) * i2,
                                 __expf(lrelu(av.w + adv.w) - m3) * i3);
    }
    __builtin_amdgcn_wave_barrier();

    auto fma8 = [&](uint4 v, float w) {
      acc[0] += w * bflo(v.x); acc[1] += w * bfhi(v.x);
      acc[2] += w * bflo(v.y); acc[3] += w * bfhi(v.y);
      acc[4] += w * bflo(v.z); acc[5] += w * bfhi(v.z);
      acc[6] += w * bflo(v.w); acc[7] += w * bfhi(v.w);
    };
    int g = 0;
    for (; g + 4 <= ne; g += 4) {
      uint4 b0 = *(const uint4*)(hb + (size_t)sl[wv][g + 0] * 1024 + loff);
      uint4 b1 = *(const uint4*)(hb + (size_t)sl[wv][g + 1] * 1024 + loff);
      uint4 b2 = *(const uint4*)(hb + (size_t)sl[wv][g + 2] * 1024 + loff);
      uint4 b3 = *(const uint4*)(hb + (size_t)sl[wv][g + 3] * 1024 + loff);
      fma8(b0, ((const float*)&wl[wv][g + 0])[myh]);
      fma8(b1, ((const float*)&wl[wv][g + 1])[myh]);
      fma8(b2, ((const float*)&wl[wv][g + 2])[myh]);
      fma8(b3, ((const float*)&wl[wv][g + 3])[myh]);
    }
    for (; g < ne; ++g) {
      uint4 b0 = *(const uint4*)(hb + (size_t)sl[wv][g] * 1024 + loff);
      fma8(b0, ((const float*)&wl[wv][g])[myh]);
    }
    __builtin_amdgcn_wave_barrier();
  }

  // head-mean across lane groups of 16 (heads live at lane strides of 16)
#pragma unroll
  for (int k = 0; k < 8; ++k) {
    acc[k] += __shfl_xor(acc[k], 16);
    acc[k] += __shfl_xor(acc[k], 32);
  }
  if (lane < 16) {
    const int c0 = lane * 8;
    const float4 bi0 = *(const float4*)&bias[c0], bi1 = *(const float4*)&bias[c0 + 4];
    const float4 g0 = *(const float4*)&bng[c0], g1 = *(const float4*)&bng[c0 + 4];
    const float4 bb0 = *(const float4*)&bnb[c0], bb1 = *(const float4*)&bnb[c0 + 4];
    const float4 mm0 = *(const float4*)&bnm[c0], mm1 = *(const float4*)&bnm[c0 + 4];
    const float4 vv0 = *(const float4*)&bnv[c0], vv1 = *(const float4*)&bnv[c0 + 4];
    const float bi[8] = {bi0.x, bi0.y, bi0.z, bi0.w, bi1.x, bi1.y, bi1.z, bi1.w};
    const float gg[8] = {g0.x, g0.y, g0.z, g0.w, g1.x, g1.y, g1.z, g1.w};
    const float bv[8] = {bb0.x, bb0.y, bb0.z, bb0.w, bb1.x, bb1.y, bb1.z, bb1.w};
    const float mv[8] = {mm0.x, mm0.y, mm0.z, mm0.w, mm1.x, mm1.y, mm1.z, mm1.w};
    const float vv[8] = {vv0.x, vv0.y, vv0.z, vv0.w, vv1.x, vv1.y, vv1.z, vv1.w};
    float o[8];
#pragma unroll
    for (int k = 0; k < 8; ++k) {
      float v = acc[k] * 0.25f + bi[k];
      float x = gg[k] * (v - mv[k]) * rsqrtf(vv[k] + 1e-5f) + bv[k];
      o[k] = fmaxf(x, 0.f);
    }
    uint4 ov;
    ov.x = pack2bf(o[0], o[1]); ov.y = pack2bf(o[2], o[3]);
    ov.z = pack2bf(o[4], o[5]); ov.w = pack2bf(o[6], o[7]);
    *(uint4*)&out[(size_t)n * 128 + c0] = ov;
  }
}

// ---------------- GAT aggregation, H=1: wave per node ----------------

__global__ __launch_bounds__(256) void gat_agg1(const bf16_t* __restrict__ h,
                                                const float* __restrict__ as,
                                                const float* __restrict__ ad,
                                                const int* __restrict__ rp,
                                                const int* __restrict__ cs,
                                                const float* __restrict__ bias,
                                                bf16_t* __restrict__ out) {
  const int wv = threadIdx.x >> 6, lane = threadIdx.x & 63;
  const int n = blockIdx.x * 4 + wv;
  __shared__ int sl[4][64];
  __shared__ float wl[4][64];

  const int r0 = rp[n], r1 = rp[n + 1];
  const float adv = ad[n];

  float mloc = -1e30f;
  for (int i = r0 + lane; i < r1; i += 64) mloc = fmaxf(mloc, lrelu(as[cs[i]] + adv));
#pragma unroll
  for (int d = 1; d < 64; d <<= 1) mloc = fmaxf(mloc, __shfl_xor(mloc, d));
  float dloc = 0.f;
  for (int i = r0 + lane; i < r1; i += 64) dloc += __expf(lrelu(as[cs[i]] + adv) - mloc);
#pragma unroll
  for (int d = 1; d < 64; d <<= 1) dloc += __shfl_xor(dloc, d);
  const float dinv = 1.f / (dloc + 1e-16f);

  const char* hb = (const char*)h;
  const size_t loff = (size_t)lane * 4;
  float a0 = 0.f, a1 = 0.f;

  for (int base = r0; base < r1; base += 64) {
    const int ne = min(64, r1 - base);
    if (lane < ne) {
      const int s = cs[base + lane];
      sl[wv][lane] = s;
      wl[wv][lane] = __expf(lrelu(as[s] + adv) - mloc) * dinv;
    }
    __builtin_amdgcn_wave_barrier();

    auto fma2 = [&](uint32_t v, float w) {
      a0 += w * bflo(v);
      a1 += w * bfhi(v);
    };
    int g = 0;
    for (; g + 4 <= ne; g += 4) {
      uint32_t b0 = *(const uint32_t*)(hb + (size_t)sl[wv][g + 0] * 256 + loff);
      uint32_t b1 = *(const uint32_t*)(hb + (size_t)sl[wv][g + 1] * 256 + loff);
      uint32_t b2 = *(const uint32_t*)(hb + (size_t)sl[wv][g + 2] * 256 + loff);
      uint32_t b3 = *(const uint32_t*)(hb + (size_t)sl[wv][g + 3] * 256 + loff);
      fma2(b0, wl[wv][g + 0]); fma2(b1, wl[wv][g + 1]);
      fma2(b2, wl[wv][g + 2]); fma2(b3, wl[wv][g + 3]);
    }
    for (; g < ne; ++g) {
      uint32_t b0 = *(const uint32_t*)(hb + (size_t)sl[wv][g] * 256 + loff);
      fma2(b0, wl[wv][g]);
    }
    __builtin_amdgcn_wave_barrier();
  }

  const int c0 = lane * 2;
  *(uint32_t*)&out[(size_t)n * 128 + c0] = pack2bf(a0 + bias[c0], a1 + bias[c0 + 1]);
}

// ---------------- launch ----------------

extern "C" void kernel_launch(void* const* d_in, const int* in_sizes, int n_in,
                              void* d_out, int out_size, void* d_ws, size_t ws_size,
                              hipStream_t stream) {
  const float* x      = (const float*)d_in[0];
  const int*   ei     = (const int*)d_in[1];
  const float* W1     = (const float*)d_in[2];
  const float* a_src1 = (const float*)d_in[3];
  const float* a_dst1 = (const float*)d_in[4];
  const float* b1     = (const float*)d_in[5];
  const float* W2     = (const float*)d_in[6];
  const float* a_src2 = (const float*)d_in[7];
  const float* a_dst2 = (const float*)d_in[8];
  const float* b2     = (const float*)d_in[9];
  const float* W3     = (const float*)d_in[10];
  const float* a_src3 = (const float*)d_in[11];
  const float* a_dst3 = (const float*)d_in[12];
  const float* b3     = (const float*)d_in[13];
  const float* bn1g = (const float*)d_in[14];
  const float* bn1b = (const float*)d_in[15];
  const float* bn1m = (const float*)d_in[16];
  const float* bn1v = (const float*)d_in[17];
  const float* bn2g = (const float*)d_in[18];
  const float* bn2b = (const float*)d_in[19];
  const float* bn2m = (const float*)d_in[20];
  const float* bn2v = (const float*)d_in[21];
  const float* l1w = (const float*)d_in[22];
  const float* l1b = (const float*)d_in[23];
  const float* l2w = (const float*)d_in[24];
  const float* l2b = (const float*)d_in[25];
  const float* l3w = (const float*)d_in[26];
  const float* l3b = (const float*)d_in[27];
  float* out = (float*)d_out;

  const int N = NN;
  const int E = in_sizes[1] / 2;
  const int ET = E + N;

  char* p = (char*)d_ws;
  auto carve = [&](size_t bytes) {
    char* q = p;
    p += (bytes + 255) & ~(size_t)255;
    return q;
  };
  bf16_t* xb   = (bf16_t*)carve((size_t)N * 256 * 2);
  bf16_t* hbig = (bf16_t*)carve((size_t)N * 512 * 2);
  bf16_t* f1b  = (bf16_t*)carve((size_t)N * 128 * 2);
  bf16_t* f2b  = (bf16_t*)carve((size_t)N * 128 * 2);
  bf16_t* g3b  = (bf16_t*)carve((size_t)N * 128 * 2);
  bf16_t* m1b  = (bf16_t*)carve((size_t)N * 128 * 2);
  bf16_t* m2b  = (bf16_t*)carve((size_t)N * 64 * 2);
  float* asb   = (float*)carve((size_t)N * 4 * 4);
  float* adb   = (float*)carve((size_t)N * 4 * 4);
  int* cnt     = (int*)carve((size_t)N * 4);
  int* cursor  = (int*)carve((size_t)N * 4);
  int* row_ptr = (int*)carve((size_t)(N + 1) * 4);
  int* col     = (int*)carve((size_t)ET * 4);
  bf16_t* W1t = (bf16_t*)carve((size_t)512 * 256 * 2);
  bf16_t* W2t = (bf16_t*)carve((size_t)512 * 128 * 2);
  bf16_t* W3t = (bf16_t*)carve((size_t)128 * 128 * 2);
  bf16_t* l1t = (bf16_t*)carve((size_t)128 * 128 * 2);
  bf16_t* l2t = (bf16_t*)carve((size_t)64 * 128 * 2);
  bf16_t* l3t = (bf16_t*)carve((size_t)64 * 64 * 2);
  (void)ws_size; (void)n_in; (void)out_size;

  // --- CSR build ---
  hipMemsetAsync(cnt, 0, (size_t)N * 4, stream);
  int eb = (ET + 255) / 256;
  hist_kernel<<<eb, 256, 0, stream>>>(ei, E, N, cnt);
  scan_kernel<<<1, 1024, 0, stream>>>(cnt, row_ptr, cursor, N);
  scatter_kernel<<<eb, 256, 0, stream>>>(ei, E, N, cursor, col);

  // --- dtype prep ---
  cast_bf16_kernel<<<(N * 256 / 4 + 255) / 256, 256, 0, stream>>>(x, xb, N * 256 / 4);
  transpose_cast<<<dim3(16, 8), dim3(32, 8), 0, stream>>>(W1, W1t, 256, 512);
  transpose_cast<<<dim3(16, 4), dim3(32, 8), 0, stream>>>(W2, W2t, 128, 512);
  transpose_cast<<<dim3(4, 4),  dim3(32, 8), 0, stream>>>(W3, W3t, 128, 128);
  transpose_cast<<<dim3(4, 4),  dim3(32, 8), 0, stream>>>(l1w, l1t, 128, 128);
  transpose_cast<<<dim3(2, 4),  dim3(32, 8), 0, stream>>>(l2w, l2t, 128, 64);
  transpose_cast<<<dim3(2, 2),  dim3(32, 8), 0, stream>>>(l3w, l3t, 64, 64);

  const int gm = (N + 127) / 128;
  const int ab = N / 4;  // 5000 blocks, wave per node

  // --- GAT layer 1 ---
  gemm_mfma<128, 0, bf16_t><<<dim3(gm, 4), 256, 0, stream>>>(xb, W1t, nullptr, hbig, N, 512, 256);
  calc_alpha4<<<ab, 256, 0, stream>>>(hbig, a_src1, a_dst1, asb, adb);
  gat_agg4<<<ab, 256, 0, stream>>>(hbig, asb, adb, row_ptr, col, b1, bn1g, bn1b, bn1m, bn1v, f1b);

  // --- GAT layer 2 ---
  gemm_mfma<128, 0, bf16_t><<<dim3(gm, 4), 256, 0, stream>>>(f1b, W2t, nullptr, hbig, N, 512, 128);
  calc_alpha4<<<ab, 256, 0, stream>>>(hbig, a_src2, a_dst2, asb, adb);
  gat_agg4<<<ab, 256, 0, stream>>>(hbig, asb, adb, row_ptr, col, b2, bn2g, bn2b, bn2m, bn2v, f2b);

  // --- GAT layer 3 (H=1) ---
  gemm_mfma<128, 0, bf16_t><<<dim3(gm, 1), 256, 0, stream>>>(f2b, W3t, nullptr, hbig, N, 128, 128);
  calc_alpha1<<<ab, 256, 0, stream>>>(hbig, a_src3, a_dst3, asb, adb);
  gat_agg1<<<ab, 256, 0, stream>>>(hbig, asb, adb, row_ptr, col, b3, g3b);

  // --- classifier MLP ---
  gemm_mfma<128, 1, bf16_t><<<dim3(gm, 1), 256, 0, stream>>>(g3b, l1t, l1b, m1b, N, 128, 128);
  gemm_mfma<64, 1, bf16_t><<<dim3(gm, 1), 256, 0, stream>>>(m1b, l2t, l2b, m2b, N, 64, 128);
  gemm_mfma<64, 2, float><<<dim3(gm, 1), 256, 0, stream>>>(m2b, l3t, l3b, out, N, 64, 64);
}

// Round 4
// 402.753 us; speedup vs baseline: 1.7408x; 1.0601x over previous
//
#include <hip/hip_runtime.h>
#include <cstdint>
#include <cstddef>

#define NN 20000

typedef __bf16 bf16_t;
typedef __bf16 bf16x8 __attribute__((ext_vector_type(8)));
typedef __bf16 bf16x4 __attribute__((ext_vector_type(4)));
typedef float f32x4 __attribute__((ext_vector_type(4)));

#define AS1 __attribute__((address_space(1)))
#define AS3 __attribute__((address_space(3)))

__device__ __forceinline__ float lrelu(float x) { return x >= 0.f ? x : 0.2f * x; }
__device__ __forceinline__ float bflo(uint32_t u) { return __uint_as_float(u << 16); }
__device__ __forceinline__ float bfhi(uint32_t u) { return __uint_as_float(u & 0xffff0000u); }

__device__ __forceinline__ uint32_t pack2bf(float a, float b) {
  bf16_t x = (bf16_t)a, y = (bf16_t)b;
  uint16_t ux = __builtin_bit_cast(uint16_t, x);
  uint16_t uy = __builtin_bit_cast(uint16_t, y);
  return (uint32_t)ux | ((uint32_t)uy << 16);
}

// ---------------- CSR build (counting sort by dst) ----------------

__global__ void hist_kernel(const int* __restrict__ ei, int E, int N, int* __restrict__ cnt) {
  int i = blockIdx.x * 256 + threadIdx.x;
  if (i < E + N) {
    int dst = (i < E) ? ei[E + i] : (i - E);
    atomicAdd(&cnt[dst], 1);
  }
}

__global__ __launch_bounds__(1024) void scan_kernel(const int* __restrict__ cnt,
                                                    int* __restrict__ row_ptr,
                                                    int* __restrict__ cursor, int n) {
  __shared__ int wsum[16];
  const int t = threadIdx.x;
  const int lane = t & 63, w = t >> 6;
  int carry = 0;
  for (int base = 0; base < n; base += 1024) {
    int i = base + t;
    int v = (i < n) ? cnt[i] : 0;
    int x = v;
#pragma unroll
    for (int d = 1; d < 64; d <<= 1) {
      int y = __shfl_up(x, d);
      if (lane >= d) x += y;
    }
    if (lane == 63) wsum[w] = x;
    __syncthreads();
    if (t < 16) {
      int s = wsum[t];
#pragma unroll
      for (int d = 1; d < 16; d <<= 1) {
        int y = __shfl_up(s, d);
        if (t >= d) s += y;
      }
      wsum[t] = s;
    }
    __syncthreads();
    int blocksum = wsum[15];
    int wprefix = (w == 0) ? 0 : wsum[w - 1];
    int excl = carry + wprefix + (x - v);
    if (i < n) { row_ptr[i] = excl; cursor[i] = excl; }
    carry += blocksum;
    __syncthreads();
  }
  if (t == 0) row_ptr[n] = carry;
}

__global__ void scatter_kernel(const int* __restrict__ ei, int E, int N,
                               int* __restrict__ cursor, int* __restrict__ col) {
  int i = blockIdx.x * 256 + threadIdx.x;
  if (i < E + N) {
    int src, dst;
    if (i < E) { src = ei[i]; dst = ei[E + i]; }
    else       { src = i - E; dst = src; }
    int slot = atomicAdd(&cursor[dst], 1);
    col[slot] = src;
  }
}

// ---------------- dtype conversion ----------------

__global__ void cast_bf16_kernel(const float* __restrict__ in, bf16_t* __restrict__ out, int n4) {
  int i = blockIdx.x * 256 + threadIdx.x;
  if (i < n4) {
    float4 v = ((const float4*)in)[i];
    bf16x4 o;
    o.x = (bf16_t)v.x; o.y = (bf16_t)v.y; o.z = (bf16_t)v.z; o.w = (bf16_t)v.w;
    ((bf16x4*)out)[i] = o;
  }
}

// batched W [K,N] fp32 -> Wt [N,K] bf16, all 6 weight matrices in one launch
struct TDesc { const float* W; bf16_t* Wt; int K; int N; int b0; };
struct TPack { TDesc d[6]; };

__global__ void transpose_cast_all(TPack p) {
  __shared__ float tile[32][33];
  int i = 5;
#pragma unroll
  for (int k = 4; k >= 0; --k)
    if ((int)blockIdx.x < p.d[k + 1].b0) i = k;
  const TDesc de = p.d[i];
  const int bi = blockIdx.x - de.b0;
  const int nbx = de.N / 32;
  const int bx = (bi % nbx) * 32;
  const int by = (bi / nbx) * 32;
  const int tx = threadIdx.x, ty = threadIdx.y;
#pragma unroll
  for (int r = 0; r < 32; r += 8)
    tile[ty + r][tx] = de.W[(size_t)(by + ty + r) * de.N + bx + tx];
  __syncthreads();
#pragma unroll
  for (int r = 0; r < 32; r += 8)
    de.Wt[(size_t)(bx + ty + r) * de.K + by + tx] = (bf16_t)tile[tx][ty + r];
}

// ---------------- bf16 MFMA GEMM: C = act(A @ Bt^T + bias) ----------------

template <int TN, int ACT, typename OUT_T>
__global__ __launch_bounds__(256) void gemm_mfma(const bf16_t* __restrict__ A,
                                                 const bf16_t* __restrict__ Bt,
                                                 const float* __restrict__ bias,
                                                 OUT_T* __restrict__ C,
                                                 int M, int N, int K) {
  constexpr int TM = 128, BK = 64;
  constexpr int MT = (TN == 128) ? 4 : 2;
  constexpr int NRB = (TN * BK * 2) / 4096;
  __shared__ __align__(16) bf16_t As[TM * BK];
  __shared__ __align__(16) bf16_t Bs[TN * BK];

  const int t = threadIdx.x;
  const int wave = t >> 6, lane = t & 63;
  const int ln15 = lane & 15, quad = lane >> 4;
  const int bm = blockIdx.x * TM;
  const int bn = blockIdx.y * TN;
  const int wm = (TN == 128) ? (wave >> 1) * 64 : wave * 32;
  const int wn = (TN == 128) ? (wave & 1) * 64 : 0;
  const int rowLimA = M - 1 - bm;
  const size_t strideAB = (size_t)K * 2;

  f32x4 acc[MT][4];
#pragma unroll
  for (int mi = 0; mi < MT; ++mi)
#pragma unroll
    for (int ni = 0; ni < 4; ++ni) acc[mi][ni] = (f32x4){0.f, 0.f, 0.f, 0.f};

  const char* gA = (const char*)(A + (size_t)bm * K);
  const char* gB = (const char*)(Bt + (size_t)bn * K);

  for (int k0 = 0; k0 < K; k0 += BK) {
#pragma unroll
    for (int r = 0; r < 4; ++r) {
      int base = (wave * 4 + r) * 1024;
      int flat = base + lane * 16;
      int row = flat >> 7;
      int grow = row < rowLimA ? row : rowLimA;
      const char* gp = gA + (size_t)grow * strideAB + (size_t)(k0 * 2) + (flat & 127);
      __builtin_amdgcn_global_load_lds((const AS1 void*)gp,
                                       (AS3 void*)((char*)As + base), 16, 0, 0);
    }
#pragma unroll
    for (int r = 0; r < NRB; ++r) {
      int base = (wave * NRB + r) * 1024;
      int flat = base + lane * 16;
      int row = flat >> 7;
      const char* gp = gB + (size_t)row * strideAB + (size_t)(k0 * 2) + (flat & 127);
      __builtin_amdgcn_global_load_lds((const AS1 void*)gp,
                                       (AS3 void*)((char*)Bs + base), 16, 0, 0);
    }
    __syncthreads();
#pragma unroll
    for (int kk = 0; kk < BK; kk += 32) {
      bf16x8 af[MT], bfr[4];
#pragma unroll
      for (int mi = 0; mi < MT; ++mi)
        af[mi] = *(const bf16x8*)&As[(wm + mi * 16 + ln15) * BK + kk + quad * 8];
#pragma unroll
      for (int ni = 0; ni < 4; ++ni)
        bfr[ni] = *(const bf16x8*)&Bs[(wn + ni * 16 + ln15) * BK + kk + quad * 8];
#pragma unroll
      for (int mi = 0; mi < MT; ++mi)
#pragma unroll
        for (int ni = 0; ni < 4; ++ni)
          acc[mi][ni] = __builtin_amdgcn_mfma_f32_16x16x32_bf16(af[mi], bfr[ni], acc[mi][ni], 0, 0, 0);
    }
    __syncthreads();
  }

#pragma unroll
  for (int mi = 0; mi < MT; ++mi) {
    int r0 = bm + wm + mi * 16 + quad * 4;
#pragma unroll
    for (int ni = 0; ni < 4; ++ni) {
      int c = bn + wn + ni * 16 + ln15;
      float bv = bias ? bias[c] : 0.f;
#pragma unroll
      for (int reg = 0; reg < 4; ++reg) {
        int r = r0 + reg;
        if (r < M) {
          float v = acc[mi][ni][reg] + bv;
          if (ACT == 1) v = fmaxf(v, 0.f);
          else if (ACT == 2) v = 1.f / (1.f + __expf(-v));
          C[(size_t)r * N + c] = (OUT_T)v;
        }
      }
    }
  }
}

// ---------------- attention logits (wave per node, 4 nodes/block) ----------------

__global__ __launch_bounds__(256) void calc_alpha4(const bf16_t* __restrict__ h,
                                                   const float* __restrict__ a_src,
                                                   const float* __restrict__ a_dst,
                                                   float* __restrict__ as_out,
                                                   float* __restrict__ ad_out) {
  const int wv = threadIdx.x >> 6, lane = threadIdx.x & 63;
  const int n = blockIdx.x * 4 + wv;
  const int c0 = lane * 8;
  const int head = lane >> 4;
  uint4 pv = *(const uint4*)&h[(size_t)n * 512 + c0];
  float4 s0 = *(const float4*)&a_src[c0];
  float4 s1 = *(const float4*)&a_src[c0 + 4];
  float4 d0 = *(const float4*)&a_dst[c0];
  float4 d1 = *(const float4*)&a_dst[c0 + 4];
  float v0 = bflo(pv.x), v1 = bfhi(pv.x), v2 = bflo(pv.y), v3 = bfhi(pv.y);
  float v4 = bflo(pv.z), v5 = bfhi(pv.z), v6 = bflo(pv.w), v7 = bfhi(pv.w);
  float ps = v0 * s0.x + v1 * s0.y + v2 * s0.z + v3 * s0.w
           + v4 * s1.x + v5 * s1.y + v6 * s1.z + v7 * s1.w;
  float pd = v0 * d0.x + v1 * d0.y + v2 * d0.z + v3 * d0.w
           + v4 * d1.x + v5 * d1.y + v6 * d1.z + v7 * d1.w;
#pragma unroll
  for (int d = 1; d < 16; d <<= 1) {
    ps += __shfl_xor(ps, d);
    pd += __shfl_xor(pd, d);
  }
  if ((lane & 15) == 0) {
    as_out[n * 4 + head] = ps;
    ad_out[n * 4 + head] = pd;
  }
}

__global__ __launch_bounds__(256) void calc_alpha1(const bf16_t* __restrict__ h,
                                                   const float* __restrict__ a_src,
                                                   const float* __restrict__ a_dst,
                                                   float* __restrict__ as_out,
                                                   float* __restrict__ ad_out) {
  const int wv = threadIdx.x >> 6, lane = threadIdx.x & 63;
  const int n = blockIdx.x * 4 + wv;
  const int c0 = lane * 2;
  uint32_t pv = *(const uint32_t*)&h[(size_t)n * 128 + c0];
  float v0 = bflo(pv), v1 = bfhi(pv);
  float ps = v0 * a_src[c0] + v1 * a_src[c0 + 1];
  float pd = v0 * a_dst[c0] + v1 * a_dst[c0 + 1];
#pragma unroll
  for (int d = 1; d < 64; d <<= 1) {
    ps += __shfl_xor(ps, d);
    pd += __shfl_xor(pd, d);
  }
  if (lane == 0) { as_out[n] = ps; ad_out[n] = pd; }
}

// ---------------- GAT aggregation, H=4: wave per (node, head-pair) ----------------
// block = 4 waves = 2 nodes x 2 head-pairs. Lane covers 8 B (4 bf16) of the
// head-pair's 512 B slice: lanes 0-31 -> head 2hp, lanes 32-63 -> head 2hp+1.

__global__ __launch_bounds__(256) void gat_agg4(const bf16_t* __restrict__ h,
                                                const float* __restrict__ as,
                                                const float* __restrict__ ad,
                                                const int* __restrict__ rp,
                                                const int* __restrict__ cs,
                                                const float* __restrict__ bias,
                                                const float* __restrict__ bng,
                                                const float* __restrict__ bnb,
                                                const float* __restrict__ bnm,
                                                const float* __restrict__ bnv,
                                                bf16_t* __restrict__ out) {
  const int w = threadIdx.x >> 6, lane = threadIdx.x & 63;
  const int nib = w >> 1;     // node within block
  const int hp = w & 1;       // head pair (heads 2hp, 2hp+1)
  const int n = blockIdx.x * 2 + nib;
  const int half = lane >> 5; // which head of the pair this lane serves
  __shared__ int sbase[4][64];       // src*1024 per edge
  __shared__ float wsel[2][4][64];   // [head-of-pair][wave][edge] alpha
  __shared__ float smf[2][2][128];   // [node][hp][col] pair-summed partials

  const int r0 = rp[n], r1 = rp[n + 1];
  const int deg = r1 - r0;
  const float2 adv = *(const float2*)&ad[n * 4 + hp * 2];
  const char* hb = (const char*)h;
  const int lboff = hp * 512 + lane * 8;

  float acc0 = 0.f, acc1 = 0.f, acc2 = 0.f, acc3 = 0.f;

  auto fma4 = [&](uint2 b, float wt) {
    acc0 += wt * bflo(b.x); acc1 += wt * bfhi(b.x);
    acc2 += wt * bflo(b.y); acc3 += wt * bfhi(b.y);
  };

  if (deg <= 64) {
    // fused single-pass: gather stats once, keep e in regs
    const bool valid = lane < deg;
    int s = 0;
    float e0 = -1e30f, e1 = -1e30f;
    if (valid) {
      s = cs[r0 + lane];
      const float2 av = *(const float2*)&as[s * 4 + hp * 2];
      e0 = lrelu(av.x + adv.x);
      e1 = lrelu(av.y + adv.y);
    }
    float m0 = e0, m1 = e1;
#pragma unroll
    for (int d = 1; d < 64; d <<= 1) {
      m0 = fmaxf(m0, __shfl_xor(m0, d));
      m1 = fmaxf(m1, __shfl_xor(m1, d));
    }
    float x0 = valid ? __expf(e0 - m0) : 0.f;
    float x1 = valid ? __expf(e1 - m1) : 0.f;
    float d0 = x0, d1 = x1;
#pragma unroll
    for (int d = 1; d < 64; d <<= 1) {
      d0 += __shfl_xor(d0, d);
      d1 += __shfl_xor(d1, d);
    }
    if (valid) {
      sbase[w][lane] = s * 1024;
      wsel[0][w][lane] = x0 / (d0 + 1e-16f);
      wsel[1][w][lane] = x1 / (d1 + 1e-16f);
    }
    __builtin_amdgcn_wave_barrier();

    int g = 0;
    for (; g + 8 <= deg; g += 8) {
      uint2 b[8];
#pragma unroll
      for (int k = 0; k < 8; ++k)
        b[k] = *(const uint2*)(hb + (size_t)(sbase[w][g + k] + lboff));
#pragma unroll
      for (int k = 0; k < 8; ++k) fma4(b[k], wsel[half][w][g + k]);
    }
    for (; g + 4 <= deg; g += 4) {
      uint2 b[4];
#pragma unroll
      for (int k = 0; k < 4; ++k)
        b[k] = *(const uint2*)(hb + (size_t)(sbase[w][g + k] + lboff));
#pragma unroll
      for (int k = 0; k < 4; ++k) fma4(b[k], wsel[half][w][g + k]);
    }
    for (; g < deg; ++g)
      fma4(*(const uint2*)(hb + (size_t)(sbase[w][g] + lboff)), wsel[half][w][g]);
  } else {
    // chunked fallback
    float m0 = -1e30f, m1 = -1e30f;
    for (int i = r0 + lane; i < r1; i += 64) {
      const float2 av = *(const float2*)&as[cs[i] * 4 + hp * 2];
      m0 = fmaxf(m0, lrelu(av.x + adv.x));
      m1 = fmaxf(m1, lrelu(av.y + adv.y));
    }
#pragma unroll
    for (int d = 1; d < 64; d <<= 1) {
      m0 = fmaxf(m0, __shfl_xor(m0, d));
      m1 = fmaxf(m1, __shfl_xor(m1, d));
    }
    float d0 = 0.f, d1 = 0.f;
    for (int i = r0 + lane; i < r1; i += 64) {
      const float2 av = *(const float2*)&as[cs[i] * 4 + hp * 2];
      d0 += __expf(lrelu(av.x + adv.x) - m0);
      d1 += __expf(lrelu(av.y + adv.y) - m1);
    }
#pragma unroll
    for (int d = 1; d < 64; d <<= 1) {
      d0 += __shfl_xor(d0, d);
      d1 += __shfl_xor(d1, d);
    }
    const float i0 = 1.f / (d0 + 1e-16f), i1 = 1.f / (d1 + 1e-16f);

    for (int base = r0; base < r1; base += 64) {
      const int ne = min(64, r1 - base);
      if (lane < ne) {
        const int s = cs[base + lane];
        const float2 av = *(const float2*)&as[s * 4 + hp * 2];
        sbase[w][lane] = s * 1024;
        wsel[0][w][lane] = __expf(lrelu(av.x + adv.x) - m0) * i0;
        wsel[1][w][lane] = __expf(lrelu(av.y + adv.y) - m1) * i1;
      }
      __builtin_amdgcn_wave_barrier();
      int g = 0;
      for (; g + 4 <= ne; g += 4) {
        uint2 b[4];
#pragma unroll
        for (int k = 0; k < 4; ++k)
          b[k] = *(const uint2*)(hb + (size_t)(sbase[w][g + k] + lboff));
#pragma unroll
        for (int k = 0; k < 4; ++k) fma4(b[k], wsel[half][w][g + k]);
      }
      for (; g < ne; ++g)
        fma4(*(const uint2*)(hb + (size_t)(sbase[w][g] + lboff)), wsel[half][w][g]);
      __builtin_amdgcn_wave_barrier();
    }
  }

  // sum the two heads of the pair (lane l and l+32 hold same head-local col)
  acc0 += __shfl_xor(acc0, 32);
  acc1 += __shfl_xor(acc1, 32);
  acc2 += __shfl_xor(acc2, 32);
  acc3 += __shfl_xor(acc3, 32);
  if (lane < 32) {
    float4 st = make_float4(acc0, acc1, acc2, acc3);
    *(float4*)&smf[nib][hp][lane * 4] = st;
  }
  __syncthreads();

  const int t = threadIdx.x;
  const int nb2 = t >> 7, c = t & 127;
  float v = (smf[nb2][0][c] + smf[nb2][1][c]) * 0.25f + bias[c];
  float xv = bng[c] * (v - bnm[c]) * rsqrtf(bnv[c] + 1e-5f) + bnb[c];
  out[(size_t)(blockIdx.x * 2 + nb2) * 128 + c] = (bf16_t)fmaxf(xv, 0.f);
}

// ---------------- GAT aggregation, H=1: wave per node ----------------

__global__ __launch_bounds__(256) void gat_agg1(const bf16_t* __restrict__ h,
                                                const float* __restrict__ as,
                                                const float* __restrict__ ad,
                                                const int* __restrict__ rp,
                                                const int* __restrict__ cs,
                                                const float* __restrict__ bias,
                                                bf16_t* __restrict__ out) {
  const int wv = threadIdx.x >> 6, lane = threadIdx.x & 63;
  const int n = blockIdx.x * 4 + wv;
  __shared__ int sl[4][64];
  __shared__ float wl[4][64];

  const int r0 = rp[n], r1 = rp[n + 1];
  const int deg = r1 - r0;
  const float adv = ad[n];
  const char* hb = (const char*)h;
  const size_t loff = (size_t)lane * 4;
  float a0 = 0.f, a1 = 0.f;

  auto fma2 = [&](uint32_t v, float w) {
    a0 += w * bflo(v);
    a1 += w * bfhi(v);
  };

  if (deg <= 64) {
    const bool valid = lane < deg;
    int s = 0;
    float e = -1e30f;
    if (valid) { s = cs[r0 + lane]; e = lrelu(as[s] + adv); }
    float m = e;
#pragma unroll
    for (int d = 1; d < 64; d <<= 1) m = fmaxf(m, __shfl_xor(m, d));
    float x = valid ? __expf(e - m) : 0.f;
    float den = x;
#pragma unroll
    for (int d = 1; d < 64; d <<= 1) den += __shfl_xor(den, d);
    if (valid) {
      sl[wv][lane] = s * 256;
      wl[wv][lane] = x / (den + 1e-16f);
    }
    __builtin_amdgcn_wave_barrier();
    int g = 0;
    for (; g + 4 <= deg; g += 4) {
      uint32_t b0 = *(const uint32_t*)(hb + (size_t)sl[wv][g + 0] + loff);
      uint32_t b1 = *(const uint32_t*)(hb + (size_t)sl[wv][g + 1] + loff);
      uint32_t b2 = *(const uint32_t*)(hb + (size_t)sl[wv][g + 2] + loff);
      uint32_t b3 = *(const uint32_t*)(hb + (size_t)sl[wv][g + 3] + loff);
      fma2(b0, wl[wv][g + 0]); fma2(b1, wl[wv][g + 1]);
      fma2(b2, wl[wv][g + 2]); fma2(b3, wl[wv][g + 3]);
    }
    for (; g < deg; ++g)
      fma2(*(const uint32_t*)(hb + (size_t)sl[wv][g] + loff), wl[wv][g]);
  } else {
    float mloc = -1e30f;
    for (int i = r0 + lane; i < r1; i += 64) mloc = fmaxf(mloc, lrelu(as[cs[i]] + adv));
#pragma unroll
    for (int d = 1; d < 64; d <<= 1) mloc = fmaxf(mloc, __shfl_xor(mloc, d));
    float dloc = 0.f;
    for (int i = r0 + lane; i < r1; i += 64) dloc += __expf(lrelu(as[cs[i]] + adv) - mloc);
#pragma unroll
    for (int d = 1; d < 64; d <<= 1) dloc += __shfl_xor(dloc, d);
    const float dinv = 1.f / (dloc + 1e-16f);

    for (int base = r0; base < r1; base += 64) {
      const int ne = min(64, r1 - base);
      if (lane < ne) {
        const int s = cs[base + lane];
        sl[wv][lane] = s * 256;
        wl[wv][lane] = __expf(lrelu(as[s] + adv) - mloc) * dinv;
      }
      __builtin_amdgcn_wave_barrier();
      int g = 0;
      for (; g + 4 <= ne; g += 4) {
        uint32_t b0 = *(const uint32_t*)(hb + (size_t)sl[wv][g + 0] + loff);
        uint32_t b1 = *(const uint32_t*)(hb + (size_t)sl[wv][g + 1] + loff);
        uint32_t b2 = *(const uint32_t*)(hb + (size_t)sl[wv][g + 2] + loff);
        uint32_t b3 = *(const uint32_t*)(hb + (size_t)sl[wv][g + 3] + loff);
        fma2(b0, wl[wv][g + 0]); fma2(b1, wl[wv][g + 1]);
        fma2(b2, wl[wv][g + 2]); fma2(b3, wl[wv][g + 3]);
      }
      for (; g < ne; ++g)
        fma2(*(const uint32_t*)(hb + (size_t)sl[wv][g] + loff), wl[wv][g]);
      __builtin_amdgcn_wave_barrier();
    }
  }

  const int c0 = lane * 2;
  *(uint32_t*)&out[(size_t)n * 128 + c0] = pack2bf(a0 + bias[c0], a1 + bias[c0 + 1]);
}

// ---------------- launch ----------------

extern "C" void kernel_launch(void* const* d_in, const int* in_sizes, int n_in,
                              void* d_out, int out_size, void* d_ws, size_t ws_size,
                              hipStream_t stream) {
  const float* x      = (const float*)d_in[0];
  const int*   ei     = (const int*)d_in[1];
  const float* W1     = (const float*)d_in[2];
  const float* a_src1 = (const float*)d_in[3];
  const float* a_dst1 = (const float*)d_in[4];
  const float* b1     = (const float*)d_in[5];
  const float* W2     = (const float*)d_in[6];
  const float* a_src2 = (const float*)d_in[7];
  const float* a_dst2 = (const float*)d_in[8];
  const float* b2     = (const float*)d_in[9];
  const float* W3     = (const float*)d_in[10];
  const float* a_src3 = (const float*)d_in[11];
  const float* a_dst3 = (const float*)d_in[12];
  const float* b3     = (const float*)d_in[13];
  const float* bn1g = (const float*)d_in[14];
  const float* bn1b = (const float*)d_in[15];
  const float* bn1m = (const float*)d_in[16];
  const float* bn1v = (const float*)d_in[17];
  const float* bn2g = (const float*)d_in[18];
  const float* bn2b = (const float*)d_in[19];
  const float* bn2m = (const float*)d_in[20];
  const float* bn2v = (const float*)d_in[21];
  const float* l1w = (const float*)d_in[22];
  const float* l1b = (const float*)d_in[23];
  const float* l2w = (const float*)d_in[24];
  const float* l2b = (const float*)d_in[25];
  const float* l3w = (const float*)d_in[26];
  const float* l3b = (const float*)d_in[27];
  float* out = (float*)d_out;

  const int N = NN;
  const int E = in_sizes[1] / 2;
  const int ET = E + N;

  char* p = (char*)d_ws;
  auto carve = [&](size_t bytes) {
    char* q = p;
    p += (bytes + 255) & ~(size_t)255;
    return q;
  };
  bf16_t* xb   = (bf16_t*)carve((size_t)N * 256 * 2);
  bf16_t* hbig = (bf16_t*)carve((size_t)N * 512 * 2);
  bf16_t* f1b  = (bf16_t*)carve((size_t)N * 128 * 2);
  bf16_t* f2b  = (bf16_t*)carve((size_t)N * 128 * 2);
  bf16_t* g3b  = (bf16_t*)carve((size_t)N * 128 * 2);
  bf16_t* m1b  = (bf16_t*)carve((size_t)N * 128 * 2);
  bf16_t* m2b  = (bf16_t*)carve((size_t)N * 64 * 2);
  float* asb   = (float*)carve((size_t)N * 4 * 4);
  float* adb   = (float*)carve((size_t)N * 4 * 4);
  int* cnt     = (int*)carve((size_t)N * 4);
  int* cursor  = (int*)carve((size_t)N * 4);
  int* row_ptr = (int*)carve((size_t)(N + 1) * 4);
  int* col     = (int*)carve((size_t)ET * 4);
  bf16_t* W1t = (bf16_t*)carve((size_t)512 * 256 * 2);
  bf16_t* W2t = (bf16_t*)carve((size_t)512 * 128 * 2);
  bf16_t* W3t = (bf16_t*)carve((size_t)128 * 128 * 2);
  bf16_t* l1t = (bf16_t*)carve((size_t)128 * 128 * 2);
  bf16_t* l2t = (bf16_t*)carve((size_t)64 * 128 * 2);
  bf16_t* l3t = (bf16_t*)carve((size_t)64 * 64 * 2);
  (void)ws_size; (void)n_in; (void)out_size;

  // --- CSR build ---
  hipMemsetAsync(cnt, 0, (size_t)N * 4, stream);
  int eb = (ET + 255) / 256;
  hist_kernel<<<eb, 256, 0, stream>>>(ei, E, N, cnt);
  scan_kernel<<<1, 1024, 0, stream>>>(cnt, row_ptr, cursor, N);
  scatter_kernel<<<eb, 256, 0, stream>>>(ei, E, N, cursor, col);

  // --- dtype prep ---
  cast_bf16_kernel<<<(N * 256 / 4 + 255) / 256, 256, 0, stream>>>(x, xb, N * 256 / 4);
  TPack tp;
  tp.d[0] = {W1,  W1t, 256, 512, 0};
  tp.d[1] = {W2,  W2t, 128, 512, 128};
  tp.d[2] = {W3,  W3t, 128, 128, 192};
  tp.d[3] = {l1w, l1t, 128, 128, 208};
  tp.d[4] = {l2w, l2t, 128, 64, 224};
  tp.d[5] = {l3w, l3t, 64, 64, 232};
  transpose_cast_all<<<236, dim3(32, 8), 0, stream>>>(tp);

  const int gm = (N + 127) / 128;
  const int ab = N / 4;   // calc_alpha / gat_agg1 blocks
  const int ab2 = N / 2;  // gat_agg4 blocks (2 nodes/block)

  // --- GAT layer 1 ---
  gemm_mfma<128, 0, bf16_t><<<dim3(gm, 4), 256, 0, stream>>>(xb, W1t, nullptr, hbig, N, 512, 256);
  calc_alpha4<<<ab, 256, 0, stream>>>(hbig, a_src1, a_dst1, asb, adb);
  gat_agg4<<<ab2, 256, 0, stream>>>(hbig, asb, adb, row_ptr, col, b1, bn1g, bn1b, bn1m, bn1v, f1b);

  // --- GAT layer 2 ---
  gemm_mfma<128, 0, bf16_t><<<dim3(gm, 4), 256, 0, stream>>>(f1b, W2t, nullptr, hbig, N, 512, 128);
  calc_alpha4<<<ab, 256, 0, stream>>>(hbig, a_src2, a_dst2, asb, adb);
  gat_agg4<<<ab2, 256, 0, stream>>>(hbig, asb, adb, row_ptr, col, b2, bn2g, bn2b, bn2m, bn2v, f2b);

  // --- GAT layer 3 (H=1) ---
  gemm_mfma<128, 0, bf16_t><<<dim3(gm, 1), 256, 0, stream>>>(f2b, W3t, nullptr, hbig, N, 128, 128);
  calc_alpha1<<<ab, 256, 0, stream>>>(hbig, a_src3, a_dst3, asb, adb);
  gat_agg1<<<ab, 256, 0, stream>>>(hbig, asb, adb, row_ptr, col, b3, g3b);

  // --- classifier MLP ---
  gemm_mfma<128, 1, bf16_t><<<dim3(gm, 1), 256, 0, stream>>>(g3b, l1t, l1b, m1b, N, 128, 128);
  gemm_mfma<64, 1, bf16_t><<<dim3(gm, 1), 256, 0, stream>>>(m1b, l2t, l2b, m2b, N, 64, 128);
  gemm_mfma<64, 2, float><<<dim3(gm, 1), 256, 0, stream>>>(m2b, l3t, l3b, out, N, 64, 64);
}

// Round 5
// 377.571 us; speedup vs baseline: 1.8569x; 1.0667x over previous
//
#include <hip/hip_runtime.h>
#include <cstdint>
#include <cstddef>

#define NN 20000

typedef __bf16 bf16_t;
typedef __bf16 bf16x8 __attribute__((ext_vector_type(8)));
typedef __bf16 bf16x4 __attribute__((ext_vector_type(4)));
typedef float f32x4 __attribute__((ext_vector_type(4)));

#define AS1 __attribute__((address_space(1)))
#define AS3 __attribute__((address_space(3)))

__device__ __forceinline__ float lrelu(float x) { return x >= 0.f ? x : 0.2f * x; }
__device__ __forceinline__ float bflo(uint32_t u) { return __uint_as_float(u << 16); }
__device__ __forceinline__ float bfhi(uint32_t u) { return __uint_as_float(u & 0xffff0000u); }

__device__ __forceinline__ uint32_t pack2bf(float a, float b) {
  bf16_t x = (bf16_t)a, y = (bf16_t)b;
  uint16_t ux = __builtin_bit_cast(uint16_t, x);
  uint16_t uy = __builtin_bit_cast(uint16_t, y);
  return (uint32_t)ux | ((uint32_t)uy << 16);
}

// ---------------- CSR build (counting sort by dst) ----------------

__global__ void hist_kernel(const int* __restrict__ ei, int E, int N, int* __restrict__ cnt) {
  int i = blockIdx.x * 256 + threadIdx.x;
  if (i < E + N) {
    int dst = (i < E) ? ei[E + i] : (i - E);
    atomicAdd(&cnt[dst], 1);
  }
}

__global__ __launch_bounds__(1024) void scan_kernel(const int* __restrict__ cnt,
                                                    int* __restrict__ row_ptr,
                                                    int* __restrict__ cursor, int n) {
  __shared__ int wsum[16];
  const int t = threadIdx.x;
  const int lane = t & 63, w = t >> 6;
  int carry = 0;
  for (int base = 0; base < n; base += 1024) {
    int i = base + t;
    int v = (i < n) ? cnt[i] : 0;
    int x = v;
#pragma unroll
    for (int d = 1; d < 64; d <<= 1) {
      int y = __shfl_up(x, d);
      if (lane >= d) x += y;
    }
    if (lane == 63) wsum[w] = x;
    __syncthreads();
    if (t < 16) {
      int s = wsum[t];
#pragma unroll
      for (int d = 1; d < 16; d <<= 1) {
        int y = __shfl_up(s, d);
        if (t >= d) s += y;
      }
      wsum[t] = s;
    }
    __syncthreads();
    int blocksum = wsum[15];
    int wprefix = (w == 0) ? 0 : wsum[w - 1];
    int excl = carry + wprefix + (x - v);
    if (i < n) { row_ptr[i] = excl; cursor[i] = excl; }
    carry += blocksum;
    __syncthreads();
  }
  if (t == 0) row_ptr[n] = carry;
}

__global__ void scatter_kernel(const int* __restrict__ ei, int E, int N,
                               int* __restrict__ cursor, int* __restrict__ col) {
  int i = blockIdx.x * 256 + threadIdx.x;
  if (i < E + N) {
    int src, dst;
    if (i < E) { src = ei[i]; dst = ei[E + i]; }
    else       { src = i - E; dst = src; }
    int slot = atomicAdd(&cursor[dst], 1);
    col[slot] = src;
  }
}

// ---------------- dtype / weight prep ----------------

__global__ void cast_bf16_kernel(const float* __restrict__ in, bf16_t* __restrict__ out, int n4) {
  int i = blockIdx.x * 256 + threadIdx.x;
  if (i < n4) {
    float4 v = ((const float4*)in)[i];
    bf16x4 o;
    o.x = (bf16_t)v.x; o.y = (bf16_t)v.y; o.z = (bf16_t)v.z; o.w = (bf16_t)v.w;
    ((bf16x4*)out)[i] = o;
  }
}

// W [K,N] fp32 -> Wt [N,K] bf16 (K,N multiples of 32)
__global__ void transpose_cast(const float* __restrict__ W, bf16_t* __restrict__ Wt,
                               int K, int N) {
  __shared__ float tile[32][33];
  const int bx = blockIdx.x * 32;
  const int by = blockIdx.y * 32;
  const int tx = threadIdx.x, ty = threadIdx.y;
#pragma unroll
  for (int i = 0; i < 32; i += 8)
    tile[ty + i][tx] = W[(size_t)(by + ty + i) * N + bx + tx];
  __syncthreads();
#pragma unroll
  for (int i = 0; i < 32; i += 8)
    Wt[(size_t)(bx + ty + i) * K + by + tx] = (bf16_t)tile[tx][ty + i];
}

// W [K, H*128] fp32 -> Bt [128, H*K] bf16 with Bt[c, h*K+k] = scale*W[k, h*128+c]
__global__ void stack_weights(const float* __restrict__ W, bf16_t* __restrict__ Bt,
                              int K, int H, float scale) {
  __shared__ float tile[32][33];
  const int kt = blockIdx.x % (K / 32), h = blockIdx.x / (K / 32);
  const int ct = blockIdx.y;
  const int tx = threadIdx.x, ty = threadIdx.y;
#pragma unroll
  for (int r = 0; r < 32; r += 8)
    tile[ty + r][tx] = W[(size_t)(kt * 32 + ty + r) * (H * 128) + h * 128 + ct * 32 + tx];
  __syncthreads();
#pragma unroll
  for (int r = 0; r < 32; r += 8)
    Bt[(size_t)(ct * 32 + ty + r) * (H * K) + h * K + kt * 32 + tx] =
        (bf16_t)(scale * tile[tx][ty + r]);
}

// P[j*K + k] = sum_c W[k, h*128+c]*a_j[h*128+c], j<H -> a_src head j, j>=H -> a_dst head j-H
__global__ __launch_bounds__(128) void alpha_proj(const float* __restrict__ W,
                                                  const float* __restrict__ a_src,
                                                  const float* __restrict__ a_dst,
                                                  float* __restrict__ P, int K, int H) {
  __shared__ float red[2];
  const int k = blockIdx.x;
  const int c = threadIdx.x;
  for (int j = 0; j < 2 * H; ++j) {
    const int h = (j < H) ? j : j - H;
    const float* a = (j < H) ? a_src : a_dst;
    float p = W[(size_t)k * (H * 128) + h * 128 + c] * a[h * 128 + c];
#pragma unroll
    for (int d = 1; d < 64; d <<= 1) p += __shfl_xor(p, d);
    if ((threadIdx.x & 63) == 0) red[threadIdx.x >> 6] = p;
    __syncthreads();
    if (threadIdx.x == 0) P[j * K + k] = red[0] + red[1];
    __syncthreads();
  }
}

// M3t[c*128+k] = (bf16)(W3 @ L1)[k,c];  bm[c] = b3 @ L1[:,c] + l1b[c]
__global__ __launch_bounds__(256) void merge_w3l1(const float* __restrict__ W3,
                                                  const float* __restrict__ L1,
                                                  const float* __restrict__ b3,
                                                  const float* __restrict__ l1b,
                                                  bf16_t* __restrict__ M3t,
                                                  float* __restrict__ bm) {
  const int idx = blockIdx.x * 256 + threadIdx.x;
  const int k = idx >> 7, c = idx & 127;
  float s = 0.f;
  for (int m = 0; m < 128; ++m) s += W3[k * 128 + m] * L1[m * 128 + c];
  M3t[c * 128 + k] = (bf16_t)s;
  if (k == 0) {
    float t = l1b[c];
    for (int m = 0; m < 128; ++m) t += b3[m] * L1[m * 128 + c];
    bm[c] = t;
  }
}

// ---------------- bf16 MFMA GEMM: C = act(A @ Bt^T + bias) ----------------
// ACT: 0=none, 1=relu, 2=sigmoid, 3=BN(eval)+relu

template <int TN, int ACT, typename OUT_T>
__global__ __launch_bounds__(256) void gemm_mfma(const bf16_t* __restrict__ A,
                                                 const bf16_t* __restrict__ Bt,
                                                 const float* __restrict__ bias,
                                                 const float* __restrict__ bng,
                                                 const float* __restrict__ bnb,
                                                 const float* __restrict__ bnm,
                                                 const float* __restrict__ bnv,
                                                 OUT_T* __restrict__ C,
                                                 int M, int N, int K) {
  constexpr int TM = 128, BK = 64;
  constexpr int MT = (TN == 128) ? 4 : 2;
  constexpr int NRB = (TN * BK * 2) / 4096;
  __shared__ __align__(16) bf16_t As[TM * BK];
  __shared__ __align__(16) bf16_t Bs[TN * BK];

  const int t = threadIdx.x;
  const int wave = t >> 6, lane = t & 63;
  const int ln15 = lane & 15, quad = lane >> 4;
  const int bm = blockIdx.x * TM;
  const int bn = blockIdx.y * TN;
  const int wm = (TN == 128) ? (wave >> 1) * 64 : wave * 32;
  const int wn = (TN == 128) ? (wave & 1) * 64 : 0;
  const int rowLimA = M - 1 - bm;
  const size_t strideAB = (size_t)K * 2;

  f32x4 acc[MT][4];
#pragma unroll
  for (int mi = 0; mi < MT; ++mi)
#pragma unroll
    for (int ni = 0; ni < 4; ++ni) acc[mi][ni] = (f32x4){0.f, 0.f, 0.f, 0.f};

  const char* gA = (const char*)(A + (size_t)bm * K);
  const char* gB = (const char*)(Bt + (size_t)bn * K);

  for (int k0 = 0; k0 < K; k0 += BK) {
#pragma unroll
    for (int r = 0; r < 4; ++r) {
      int base = (wave * 4 + r) * 1024;
      int flat = base + lane * 16;
      int row = flat >> 7;
      int grow = row < rowLimA ? row : rowLimA;
      const char* gp = gA + (size_t)grow * strideAB + (size_t)(k0 * 2) + (flat & 127);
      __builtin_amdgcn_global_load_lds((const AS1 void*)gp,
                                       (AS3 void*)((char*)As + base), 16, 0, 0);
    }
#pragma unroll
    for (int r = 0; r < NRB; ++r) {
      int base = (wave * NRB + r) * 1024;
      int flat = base + lane * 16;
      int row = flat >> 7;
      const char* gp = gB + (size_t)row * strideAB + (size_t)(k0 * 2) + (flat & 127);
      __builtin_amdgcn_global_load_lds((const AS1 void*)gp,
                                       (AS3 void*)((char*)Bs + base), 16, 0, 0);
    }
    __syncthreads();
#pragma unroll
    for (int kk = 0; kk < BK; kk += 32) {
      bf16x8 af[MT], bfr[4];
#pragma unroll
      for (int mi = 0; mi < MT; ++mi)
        af[mi] = *(const bf16x8*)&As[(wm + mi * 16 + ln15) * BK + kk + quad * 8];
#pragma unroll
      for (int ni = 0; ni < 4; ++ni)
        bfr[ni] = *(const bf16x8*)&Bs[(wn + ni * 16 + ln15) * BK + kk + quad * 8];
#pragma unroll
      for (int mi = 0; mi < MT; ++mi)
#pragma unroll
        for (int ni = 0; ni < 4; ++ni)
          acc[mi][ni] = __builtin_amdgcn_mfma_f32_16x16x32_bf16(af[mi], bfr[ni], acc[mi][ni], 0, 0, 0);
    }
    __syncthreads();
  }

#pragma unroll
  for (int mi = 0; mi < MT; ++mi) {
    int r0 = bm + wm + mi * 16 + quad * 4;
#pragma unroll
    for (int ni = 0; ni < 4; ++ni) {
      int c = bn + wn + ni * 16 + ln15;
      float bv = bias ? bias[c] : 0.f;
      float sc = 1.f, sh = 0.f;
      if (ACT == 3) {
        sc = bng[c] * rsqrtf(bnv[c] + 1e-5f);
        sh = bnb[c] - bnm[c] * sc;
      }
#pragma unroll
      for (int reg = 0; reg < 4; ++reg) {
        int r = r0 + reg;
        if (r < M) {
          float v = acc[mi][ni][reg] + bv;
          if (ACT == 1) v = fmaxf(v, 0.f);
          else if (ACT == 2) v = 1.f / (1.f + __expf(-v));
          else if (ACT == 3) v = fmaxf(v * sc + sh, 0.f);
          C[(size_t)r * N + c] = (OUT_T)v;
        }
      }
    }
  }
}

// ---------------- alpha logits: asad[n, j] = f[n,:] . P[j,:]  (j < 2H) ----------------

template <int K, int H>
__global__ __launch_bounds__(256) void alpha_gemm(const bf16_t* __restrict__ f,
                                                  const float* __restrict__ P,
                                                  float* __restrict__ asad) {
  constexpr int J = 2 * H;
  constexpr int KC = K / 64;
  const int wv = threadIdx.x >> 6, lane = threadIdx.x & 63;
  const int n = blockIdx.x * 4 + wv;
  float v[KC];
  if (KC == 4) {
    uint2 pv = *(const uint2*)&f[(size_t)n * K + lane * 4];
    v[0] = bflo(pv.x); v[1] = bfhi(pv.x); v[2] = bflo(pv.y); v[3] = bfhi(pv.y);
  } else {
    uint32_t pv = *(const uint32_t*)&f[(size_t)n * K + lane * 2];
    v[0] = bflo(pv); v[1] = bfhi(pv);
  }
  float s[J];
#pragma unroll
  for (int j = 0; j < J; ++j) {
    float acc = 0.f;
#pragma unroll
    for (int q = 0; q < KC; ++q) acc += v[q] * P[j * K + lane * KC + q];
    s[j] = acc;
  }
#pragma unroll
  for (int j = 0; j < J; ++j)
#pragma unroll
    for (int d = 1; d < 64; d <<= 1) s[j] += __shfl_xor(s[j], d);
  if (lane == 0) {
#pragma unroll
    for (int j = 0; j < J; ++j) asad[(size_t)n * J + j] = s[j];
  }
}

// ---------------- input-space GAT aggregation, H=4: wave per node ----------------
// agg[n, h*K + k] = sum_e alpha_e^h * f[src_e, k]

template <int K>
__global__ __launch_bounds__(256) void gat_agg_in4(const bf16_t* __restrict__ f,
                                                   const float* __restrict__ asad,
                                                   const int* __restrict__ rp,
                                                   const int* __restrict__ cs,
                                                   bf16_t* __restrict__ agg) {
  constexpr int KC = K / 64;  // bf16 per lane (4 or 2)
  const int wv = threadIdx.x >> 6, lane = threadIdx.x & 63;
  const int n = blockIdx.x * 4 + wv;
  __shared__ int sb[4][64];
  __shared__ float4 wl[4][64];

  const int r0 = rp[n], r1 = rp[n + 1];
  const int deg = r1 - r0;
  const float4 adv = *(const float4*)&asad[(size_t)n * 8 + 4];
  const char* fb = (const char*)f;
  const size_t loff = (size_t)lane * (KC * 2);

  float acc[4][KC];
#pragma unroll
  for (int j = 0; j < 4; ++j)
#pragma unroll
    for (int q = 0; q < KC; ++q) acc[j][q] = 0.f;

  auto edge_fma = [&](const char* gp, float4 w4) {
    if (KC == 4) {
      uint2 b = *(const uint2*)gp;
      float v0 = bflo(b.x), v1 = bfhi(b.x), v2 = bflo(b.y), v3 = bfhi(b.y);
      acc[0][0] += w4.x * v0; acc[0][1] += w4.x * v1; acc[0][2] += w4.x * v2; acc[0][3] += w4.x * v3;
      acc[1][0] += w4.y * v0; acc[1][1] += w4.y * v1; acc[1][2] += w4.y * v2; acc[1][3] += w4.y * v3;
      acc[2][0] += w4.z * v0; acc[2][1] += w4.z * v1; acc[2][2] += w4.z * v2; acc[2][3] += w4.z * v3;
      acc[3][0] += w4.w * v0; acc[3][1] += w4.w * v1; acc[3][2] += w4.w * v2; acc[3][3] += w4.w * v3;
    } else {
      uint32_t b = *(const uint32_t*)gp;
      float v0 = bflo(b), v1 = bfhi(b);
      acc[0][0] += w4.x * v0; acc[0][1] += w4.x * v1;
      acc[1][0] += w4.y * v0; acc[1][1] += w4.y * v1;
      acc[2][0] += w4.z * v0; acc[2][1] += w4.z * v1;
      acc[3][0] += w4.w * v0; acc[3][1] += w4.w * v1;
    }
  };

  if (deg <= 64) {
    const bool valid = lane < deg;
    int s = 0;
    float e0 = -1e30f, e1 = -1e30f, e2 = -1e30f, e3 = -1e30f;
    if (valid) {
      s = cs[r0 + lane];
      const float4 av = *(const float4*)&asad[(size_t)s * 8];
      e0 = lrelu(av.x + adv.x); e1 = lrelu(av.y + adv.y);
      e2 = lrelu(av.z + adv.z); e3 = lrelu(av.w + adv.w);
    }
    float m0 = e0, m1 = e1, m2 = e2, m3 = e3;
#pragma unroll
    for (int d = 1; d < 64; d <<= 1) {
      m0 = fmaxf(m0, __shfl_xor(m0, d)); m1 = fmaxf(m1, __shfl_xor(m1, d));
      m2 = fmaxf(m2, __shfl_xor(m2, d)); m3 = fmaxf(m3, __shfl_xor(m3, d));
    }
    float x0 = valid ? __expf(e0 - m0) : 0.f;
    float x1 = valid ? __expf(e1 - m1) : 0.f;
    float x2 = valid ? __expf(e2 - m2) : 0.f;
    float x3 = valid ? __expf(e3 - m3) : 0.f;
    float d0 = x0, d1 = x1, d2 = x2, d3 = x3;
#pragma unroll
    for (int d = 1; d < 64; d <<= 1) {
      d0 += __shfl_xor(d0, d); d1 += __shfl_xor(d1, d);
      d2 += __shfl_xor(d2, d); d3 += __shfl_xor(d3, d);
    }
    if (valid) {
      sb[wv][lane] = s * (K * 2);
      wl[wv][lane] = make_float4(x0 / (d0 + 1e-16f), x1 / (d1 + 1e-16f),
                                 x2 / (d2 + 1e-16f), x3 / (d3 + 1e-16f));
    }
    __builtin_amdgcn_wave_barrier();

    int g = 0;
    for (; g + 4 <= deg; g += 4) {
      const char* p0 = fb + (size_t)sb[wv][g + 0] + loff;
      const char* p1 = fb + (size_t)sb[wv][g + 1] + loff;
      const char* p2 = fb + (size_t)sb[wv][g + 2] + loff;
      const char* p3 = fb + (size_t)sb[wv][g + 3] + loff;
      float4 w0 = wl[wv][g + 0], w1 = wl[wv][g + 1];
      float4 w2 = wl[wv][g + 2], w3 = wl[wv][g + 3];
      edge_fma(p0, w0); edge_fma(p1, w1); edge_fma(p2, w2); edge_fma(p3, w3);
    }
    for (; g < deg; ++g)
      edge_fma(fb + (size_t)sb[wv][g] + loff, wl[wv][g]);
  } else {
    // chunked fallback (deg > 64)
    float m0 = -1e30f, m1 = -1e30f, m2 = -1e30f, m3 = -1e30f;
    for (int i = r0 + lane; i < r1; i += 64) {
      const float4 av = *(const float4*)&asad[(size_t)cs[i] * 8];
      m0 = fmaxf(m0, lrelu(av.x + adv.x)); m1 = fmaxf(m1, lrelu(av.y + adv.y));
      m2 = fmaxf(m2, lrelu(av.z + adv.z)); m3 = fmaxf(m3, lrelu(av.w + adv.w));
    }
#pragma unroll
    for (int d = 1; d < 64; d <<= 1) {
      m0 = fmaxf(m0, __shfl_xor(m0, d)); m1 = fmaxf(m1, __shfl_xor(m1, d));
      m2 = fmaxf(m2, __shfl_xor(m2, d)); m3 = fmaxf(m3, __shfl_xor(m3, d));
    }
    float d0 = 0.f, d1 = 0.f, d2 = 0.f, d3 = 0.f;
    for (int i = r0 + lane; i < r1; i += 64) {
      const float4 av = *(const float4*)&asad[(size_t)cs[i] * 8];
      d0 += __expf(lrelu(av.x + adv.x) - m0); d1 += __expf(lrelu(av.y + adv.y) - m1);
      d2 += __expf(lrelu(av.z + adv.z) - m2); d3 += __expf(lrelu(av.w + adv.w) - m3);
    }
#pragma unroll
    for (int d = 1; d < 64; d <<= 1) {
      d0 += __shfl_xor(d0, d); d1 += __shfl_xor(d1, d);
      d2 += __shfl_xor(d2, d); d3 += __shfl_xor(d3, d);
    }
    const float i0 = 1.f / (d0 + 1e-16f), i1 = 1.f / (d1 + 1e-16f);
    const float i2 = 1.f / (d2 + 1e-16f), i3 = 1.f / (d3 + 1e-16f);
    for (int base = r0; base < r1; base += 64) {
      const int ne = min(64, r1 - base);
      if (lane < ne) {
        const int s = cs[base + lane];
        const float4 av = *(const float4*)&asad[(size_t)s * 8];
        sb[wv][lane] = s * (K * 2);
        wl[wv][lane] = make_float4(__expf(lrelu(av.x + adv.x) - m0) * i0,
                                   __expf(lrelu(av.y + adv.y) - m1) * i1,
                                   __expf(lrelu(av.z + adv.z) - m2) * i2,
                                   __expf(lrelu(av.w + adv.w) - m3) * i3);
      }
      __builtin_amdgcn_wave_barrier();
      for (int g = 0; g < ne; ++g)
        edge_fma(fb + (size_t)sb[wv][g] + loff, wl[wv][g]);
      __builtin_amdgcn_wave_barrier();
    }
  }

  // store agg row [4 heads][K], lane covers KC cols per head
#pragma unroll
  for (int j = 0; j < 4; ++j) {
    if (KC == 4) {
      uint2 ov;
      ov.x = pack2bf(acc[j][0], acc[j][1]);
      ov.y = pack2bf(acc[j][2], acc[j][3]);
      *(uint2*)&agg[(size_t)n * (4 * K) + j * K + lane * 4] = ov;
    } else {
      *(uint32_t*)&agg[(size_t)n * (4 * K) + j * K + lane * 2] = pack2bf(acc[j][0], acc[j][1]);
    }
  }
}

// ---------------- input-space GAT aggregation, H=1 (K=128): wave per node --------------

__global__ __launch_bounds__(256) void gat_agg_in1(const bf16_t* __restrict__ f,
                                                   const float* __restrict__ asad,
                                                   const int* __restrict__ rp,
                                                   const int* __restrict__ cs,
                                                   bf16_t* __restrict__ agg) {
  const int wv = threadIdx.x >> 6, lane = threadIdx.x & 63;
  const int n = blockIdx.x * 4 + wv;
  __shared__ int sb[4][64];
  __shared__ float wl[4][64];

  const int r0 = rp[n], r1 = rp[n + 1];
  const int deg = r1 - r0;
  const float adv = asad[(size_t)n * 2 + 1];
  const char* fb = (const char*)f;
  const size_t loff = (size_t)lane * 4;
  float a0 = 0.f, a1 = 0.f;

  auto fma2 = [&](uint32_t v, float w) { a0 += w * bflo(v); a1 += w * bfhi(v); };

  if (deg <= 64) {
    const bool valid = lane < deg;
    int s = 0;
    float e = -1e30f;
    if (valid) { s = cs[r0 + lane]; e = lrelu(asad[(size_t)s * 2] + adv); }
    float m = e;
#pragma unroll
    for (int d = 1; d < 64; d <<= 1) m = fmaxf(m, __shfl_xor(m, d));
    float x = valid ? __expf(e - m) : 0.f;
    float den = x;
#pragma unroll
    for (int d = 1; d < 64; d <<= 1) den += __shfl_xor(den, d);
    if (valid) { sb[wv][lane] = s * 256; wl[wv][lane] = x / (den + 1e-16f); }
    __builtin_amdgcn_wave_barrier();
    int g = 0;
    for (; g + 4 <= deg; g += 4) {
      uint32_t b0 = *(const uint32_t*)(fb + (size_t)sb[wv][g + 0] + loff);
      uint32_t b1 = *(const uint32_t*)(fb + (size_t)sb[wv][g + 1] + loff);
      uint32_t b2 = *(const uint32_t*)(fb + (size_t)sb[wv][g + 2] + loff);
      uint32_t b3 = *(const uint32_t*)(fb + (size_t)sb[wv][g + 3] + loff);
      fma2(b0, wl[wv][g + 0]); fma2(b1, wl[wv][g + 1]);
      fma2(b2, wl[wv][g + 2]); fma2(b3, wl[wv][g + 3]);
    }
    for (; g < deg; ++g)
      fma2(*(const uint32_t*)(fb + (size_t)sb[wv][g] + loff), wl[wv][g]);
  } else {
    float m = -1e30f;
    for (int i = r0 + lane; i < r1; i += 64) m = fmaxf(m, lrelu(asad[(size_t)cs[i] * 2] + adv));
#pragma unroll
    for (int d = 1; d < 64; d <<= 1) m = fmaxf(m, __shfl_xor(m, d));
    float den = 0.f;
    for (int i = r0 + lane; i < r1; i += 64) den += __expf(lrelu(asad[(size_t)cs[i] * 2] + adv) - m);
#pragma unroll
    for (int d = 1; d < 64; d <<= 1) den += __shfl_xor(den, d);
    const float dinv = 1.f / (den + 1e-16f);
    for (int base = r0; base < r1; base += 64) {
      const int ne = min(64, r1 - base);
      if (lane < ne) {
        const int s = cs[base + lane];
        sb[wv][lane] = s * 256;
        wl[wv][lane] = __expf(lrelu(asad[(size_t)s * 2] + adv) - m) * dinv;
      }
      __builtin_amdgcn_wave_barrier();
      for (int g = 0; g < ne; ++g)
        fma2(*(const uint32_t*)(fb + (size_t)sb[wv][g] + loff), wl[wv][g]);
      __builtin_amdgcn_wave_barrier();
    }
  }
  *(uint32_t*)&agg[(size_t)n * 128 + lane * 2] = pack2bf(a0, a1);
}

// ---------------- launch ----------------

extern "C" void kernel_launch(void* const* d_in, const int* in_sizes, int n_in,
                              void* d_out, int out_size, void* d_ws, size_t ws_size,
                              hipStream_t stream) {
  const float* x      = (const float*)d_in[0];
  const int*   ei     = (const int*)d_in[1];
  const float* W1     = (const float*)d_in[2];
  const float* a_src1 = (const float*)d_in[3];
  const float* a_dst1 = (const float*)d_in[4];
  const float* b1     = (const float*)d_in[5];
  const float* W2     = (const float*)d_in[6];
  const float* a_src2 = (const float*)d_in[7];
  const float* a_dst2 = (const float*)d_in[8];
  const float* b2     = (const float*)d_in[9];
  const float* W3     = (const float*)d_in[10];
  const float* a_src3 = (const float*)d_in[11];
  const float* a_dst3 = (const float*)d_in[12];
  const float* b3     = (const float*)d_in[13];
  const float* bn1g = (const float*)d_in[14];
  const float* bn1b = (const float*)d_in[15];
  const float* bn1m = (const float*)d_in[16];
  const float* bn1v = (const float*)d_in[17];
  const float* bn2g = (const float*)d_in[18];
  const float* bn2b = (const float*)d_in[19];
  const float* bn2m = (const float*)d_in[20];
  const float* bn2v = (const float*)d_in[21];
  const float* l1w = (const float*)d_in[22];
  const float* l1b = (const float*)d_in[23];
  const float* l2w = (const float*)d_in[24];
  const float* l2b = (const float*)d_in[25];
  const float* l3w = (const float*)d_in[26];
  const float* l3b = (const float*)d_in[27];
  float* out = (float*)d_out;

  const int N = NN;
  const int E = in_sizes[1] / 2;
  const int ET = E + N;

  char* p = (char*)d_ws;
  auto carve = [&](size_t bytes) {
    char* q = p;
    p += (bytes + 255) & ~(size_t)255;
    return q;
  };
  bf16_t* xb    = (bf16_t*)carve((size_t)N * 256 * 2);   // 10.24 MB
  char*   aggr  = carve((size_t)N * 1024 * 2);           // 40.96 MB (shared/aliased)
  bf16_t* f1b   = (bf16_t*)carve((size_t)N * 128 * 2);
  bf16_t* f2b   = (bf16_t*)carve((size_t)N * 128 * 2);
  float* asad   = (float*)carve((size_t)N * 8 * 4);
  int* cnt      = (int*)carve((size_t)N * 4);
  int* cursor   = (int*)carve((size_t)N * 4);
  int* row_ptr  = (int*)carve((size_t)(N + 1) * 4);
  int* col      = (int*)carve((size_t)ET * 4);
  bf16_t* Ws1t  = (bf16_t*)carve((size_t)128 * 1024 * 2);
  bf16_t* Ws2t  = (bf16_t*)carve((size_t)128 * 512 * 2);
  bf16_t* M3t   = (bf16_t*)carve((size_t)128 * 128 * 2);
  bf16_t* l2t   = (bf16_t*)carve((size_t)64 * 128 * 2);
  bf16_t* l3t   = (bf16_t*)carve((size_t)64 * 64 * 2);
  float* P1     = (float*)carve((size_t)8 * 256 * 4);
  float* P2     = (float*)carve((size_t)8 * 128 * 4);
  float* P3     = (float*)carve((size_t)2 * 128 * 4);
  float* bm     = (float*)carve((size_t)128 * 4);
  (void)ws_size; (void)n_in; (void)out_size;

  // alias MLP intermediates into dead regions of aggr
  bf16_t* aggb = (bf16_t*)aggr;                          // layer aggregates / agg3
  bf16_t* m1b  = (bf16_t*)(aggr + (8u << 20));           // [N,128] at +8 MiB
  bf16_t* m2b  = (bf16_t*)(aggr + (16u << 20));          // [N,64]  at +16 MiB

  // --- CSR build ---
  hipMemsetAsync(cnt, 0, (size_t)N * 4, stream);
  int eb = (ET + 255) / 256;
  hist_kernel<<<eb, 256, 0, stream>>>(ei, E, N, cnt);
  scan_kernel<<<1, 1024, 0, stream>>>(cnt, row_ptr, cursor, N);
  scatter_kernel<<<eb, 256, 0, stream>>>(ei, E, N, cursor, col);

  // --- prep ---
  cast_bf16_kernel<<<(N * 256 / 4 + 255) / 256, 256, 0, stream>>>(x, xb, N * 256 / 4);
  stack_weights<<<dim3(4 * 8, 4), dim3(32, 8), 0, stream>>>(W1, Ws1t, 256, 4, 0.25f);
  stack_weights<<<dim3(4 * 4, 4), dim3(32, 8), 0, stream>>>(W2, Ws2t, 128, 4, 0.25f);
  transpose_cast<<<dim3(2, 4), dim3(32, 8), 0, stream>>>(l2w, l2t, 128, 64);
  transpose_cast<<<dim3(2, 2), dim3(32, 8), 0, stream>>>(l3w, l3t, 64, 64);
  alpha_proj<<<256, 128, 0, stream>>>(W1, a_src1, a_dst1, P1, 256, 4);
  alpha_proj<<<128, 128, 0, stream>>>(W2, a_src2, a_dst2, P2, 128, 4);
  alpha_proj<<<128, 128, 0, stream>>>(W3, a_src3, a_dst3, P3, 128, 1);
  merge_w3l1<<<64, 256, 0, stream>>>(W3, l1w, b3, l1b, M3t, bm);

  const int gm = (N + 127) / 128;  // 157
  const int ab = N / 4;            // 5000

  // --- GAT layer 1 (input-space aggregation) ---
  alpha_gemm<256, 4><<<ab, 256, 0, stream>>>(xb, P1, asad);
  gat_agg_in4<256><<<ab, 256, 0, stream>>>(xb, asad, row_ptr, col, aggb);
  gemm_mfma<64, 3, bf16_t><<<dim3(gm, 2), 256, 0, stream>>>(
      aggb, Ws1t, b1, bn1g, bn1b, bn1m, bn1v, f1b, N, 128, 1024);

  // --- GAT layer 2 ---
  alpha_gemm<128, 4><<<ab, 256, 0, stream>>>(f1b, P2, asad);
  gat_agg_in4<128><<<ab, 256, 0, stream>>>(f1b, asad, row_ptr, col, aggb);
  gemm_mfma<64, 3, bf16_t><<<dim3(gm, 2), 256, 0, stream>>>(
      aggb, Ws2t, b2, bn2g, bn2b, bn2m, bn2v, f2b, N, 128, 512);

  // --- GAT layer 3 (H=1) fused with classifier l1 ---
  alpha_gemm<128, 1><<<ab, 256, 0, stream>>>(f2b, P3, asad);
  gat_agg_in1<<<ab, 256, 0, stream>>>(f2b, asad, row_ptr, col, aggb);
  gemm_mfma<64, 1, bf16_t><<<dim3(gm, 2), 256, 0, stream>>>(
      aggb, M3t, bm, nullptr, nullptr, nullptr, nullptr, m1b, N, 128, 128);

  // --- classifier tail ---
  gemm_mfma<64, 1, bf16_t><<<dim3(gm, 1), 256, 0, stream>>>(
      m1b, l2t, l2b, nullptr, nullptr, nullptr, nullptr, m2b, N, 64, 128);
  gemm_mfma<64, 2, float><<<dim3(gm, 1), 256, 0, stream>>>(
      m2b, l3t, l3b, nullptr, nullptr, nullptr, nullptr, out, N, 64, 64);
}